// Round 1
// baseline (1519.002 us; speedup 1.0000x reference)
//
#include <hip/hip_runtime.h>

// StateSpaceModel: y = scan(h = h@A + x@B) @ C,  B=32 L=2048 D=512.
// Restructured chunked scan, all phases as parallel big-M GEMMs:
//   u = x@B                                  (kt_gemm_rows)
//   h0 (zero-init chunk scans, ALL stored):  7x kt_step, each M=8192 GEMM,
//       h0[c,0] = u[c,0] implicitly (read from u where needed)
//   Kogge-Stone over 256 chunk summaries:    8x kt_ks2 (summaries = h0[c,7])
//   y[c,j] = h0[c,j]@C + P_{c-1}@(A^{j+1}C)  (kt_out, one K=1024 GEMM,
//       taps T_{j+1}=A^{j+1}C precomputed; LDS-staged full-line fp32 stores)

using bf16 = __bf16;
typedef __bf16 bf16x8 __attribute__((ext_vector_type(8)));
typedef float  f32x4  __attribute__((ext_vector_type(4)));

constexpr int Dm   = 512;
constexpr int Lseq = 2048;
constexpr int KC   = 8;    // chunk length
constexpr int CH   = 256;  // chunks

__device__ __forceinline__ bf16x8 ld8(const bf16* p) {
  return *reinterpret_cast<const bf16x8*>(p);
}
__device__ __forceinline__ bf16x8 ld8f(const float* p) {
  f32x4 lo = *reinterpret_cast<const f32x4*>(p);
  f32x4 hi = *reinterpret_cast<const f32x4*>(p + 4);
  bf16x8 r;
#pragma unroll
  for (int i = 0; i < 4; ++i) { r[i] = (bf16)lo[i]; r[i + 4] = (bf16)hi[i]; }
  return r;
}
__device__ __forceinline__ f32x4 mfma16(bf16x8 a, bf16x8 b, f32x4 c) {
  return __builtin_amdgcn_mfma_f32_16x16x32_bf16(a, b, c, 0, 0, 0);
}

// 32-row GEMM core for one wave: rows r=l16 (pA0) and r=16+l16 (pA1), K=Dm,
// 4 col-tiles of 16 starting at BtN = Bt + nbase*Dm. Barrier-free, operands
// straight from global (L2). acc rows: quad*4+r (+16 for mt=1), col l16.
__device__ __forceinline__ void gemm_core(const bf16* pA0, const bf16* pA1,
                                          const bf16* BtN, int quad, int l16,
                                          f32x4 acc[2][4]) {
  for (int kk = 0; kk < Dm; kk += 32) {
    const int kf = kk + quad * 8;
    bf16x8 a0 = ld8(pA0 + kf);
    bf16x8 a1 = ld8(pA1 + kf);
#pragma unroll
    for (int nt = 0; nt < 4; ++nt) {
      bf16x8 bw = ld8(BtN + (long)(nt * 16 + l16) * Dm + kf);
      acc[0][nt] = mfma16(a0, bw, acc[0][nt]);
      acc[1][nt] = mfma16(a1, bw, acc[1][nt]);
    }
  }
}

// ---- pack fp32->bf16: Wt[n][k] = W[k][n] for deltaA/deltaB/C, Abf=A, zero row ----
__global__ __launch_bounds__(256) void kt_pack(
    const float* __restrict__ a, const float* __restrict__ b, const float* __restrict__ c,
    bf16* __restrict__ at, bf16* __restrict__ bt, bf16* __restrict__ ct,
    bf16* __restrict__ abf, bf16* __restrict__ zrow) {
  if (blockIdx.y == 0 && blockIdx.x == 0 && threadIdx.x < 256)
    reinterpret_cast<int*>(zrow)[threadIdx.x] = 0;  // 1 KB of zeros
  int flat = blockIdx.x * 256 + threadIdx.x;
  int n = flat & (Dm - 1);
  int k = flat >> 9;
  const float* s = (blockIdx.y == 0) ? a : (blockIdx.y == 1) ? b : c;
  bf16* d        = (blockIdx.y == 0) ? at : (blockIdx.y == 1) ? bt : ct;
  float v = s[(long)k * Dm + n];
  d[(long)n * Dm + k] = (bf16)v;
  if (blockIdx.y == 0) abf[(long)k * Dm + n] = (bf16)v;
}

// ---- u = x @ deltaB : fp32 rows -> bf16 out ----
__global__ __launch_bounds__(512) void kt_gemm_rows(
    const float* __restrict__ X, const bf16* __restrict__ Wt, bf16* __restrict__ O) {
  const int tid = threadIdx.x;
  const int wave = tid >> 6, lane = tid & 63;
  const int quad = lane >> 4, l16 = lane & 15;
  const long rowbase = (long)blockIdx.x * 32;
  const int nbase = wave * 64;
  f32x4 acc[2][4] = {};
  for (int kk = 0; kk < Dm; kk += 32) {
    const int kf = kk + quad * 8;
    bf16x8 a0 = ld8f(X + (rowbase + l16) * Dm + kf);
    bf16x8 a1 = ld8f(X + (rowbase + 16 + l16) * Dm + kf);
#pragma unroll
    for (int nt = 0; nt < 4; ++nt) {
      bf16x8 bw = ld8(Wt + (long)(nbase + nt * 16 + l16) * Dm + kf);
      acc[0][nt] = mfma16(a0, bw, acc[0][nt]);
      acc[1][nt] = mfma16(a1, bw, acc[1][nt]);
    }
  }
#pragma unroll
  for (int mt = 0; mt < 2; ++mt)
#pragma unroll
    for (int nt = 0; nt < 4; ++nt)
#pragma unroll
      for (int r = 0; r < 4; ++r) {
        long m = rowbase + mt * 16 + quad * 4 + r;
        int n = nbase + nt * 16 + l16;
        O[m * Dm + n] = (bf16)acc[mt][nt][r];
      }
}

// ---- S = Aop @ B (Bt given transposed); writes S and S^T ----
__global__ __launch_bounds__(512) void kt_square(
    const bf16* __restrict__ P, const bf16* __restrict__ Pt,
    bf16* __restrict__ S, bf16* __restrict__ St) {
  const int tid = threadIdx.x;
  const int wave = tid >> 6, lane = tid & 63;
  const int quad = lane >> 4, l16 = lane & 15;
  const long rowbase = (long)blockIdx.x * 32;
  const int nbase = wave * 64;
  f32x4 acc[2][4] = {};
  gemm_core(P + (rowbase + l16) * Dm, P + (rowbase + 16 + l16) * Dm,
            Pt + (long)nbase * Dm, quad, l16, acc);
#pragma unroll
  for (int mt = 0; mt < 2; ++mt)
#pragma unroll
    for (int nt = 0; nt < 4; ++nt)
#pragma unroll
      for (int r = 0; r < 4; ++r) {
        long m = rowbase + mt * 16 + quad * 4 + r;
        int n = nbase + nt * 16 + l16;
        float v = acc[mt][nt][r];
        S[m * Dm + n] = (bf16)v;
        St[(long)n * Dm + m] = (bf16)v;
      }
}

// ---- taps: Tt[j] = (A^(j+1) @ C)^T, j = blockIdx.y in 0..7 ----
__global__ __launch_bounds__(512) void kt_taps(
    const bf16* __restrict__ q1, const bf16* __restrict__ q2,
    const bf16* __restrict__ q3, const bf16* __restrict__ q4,
    const bf16* __restrict__ q5, const bf16* __restrict__ q6,
    const bf16* __restrict__ q7, const bf16* __restrict__ q8,
    const bf16* __restrict__ Ct, bf16* __restrict__ Tt) {
  const int j = blockIdx.y;
  const bf16* Aop = (j == 0) ? q1 : (j == 1) ? q2 : (j == 2) ? q3 : (j == 3) ? q4
                  : (j == 4) ? q5 : (j == 5) ? q6 : (j == 6) ? q7 : q8;
  bf16* St = Tt + (long)j * Dm * Dm;
  const int tid = threadIdx.x;
  const int wave = tid >> 6, lane = tid & 63;
  const int quad = lane >> 4, l16 = lane & 15;
  const long rowbase = (long)blockIdx.x * 32;
  const int nbase = wave * 64;
  f32x4 acc[2][4] = {};
  gemm_core(Aop + (rowbase + l16) * Dm, Aop + (rowbase + 16 + l16) * Dm,
            Ct + (long)nbase * Dm, quad, l16, acc);
#pragma unroll
  for (int mt = 0; mt < 2; ++mt)
#pragma unroll
    for (int nt = 0; nt < 4; ++nt)
#pragma unroll
      for (int r = 0; r < 4; ++r) {
        long m = rowbase + mt * 16 + quad * 4 + r;
        int n = nbase + nt * 16 + l16;
        St[(long)n * Dm + m] = (bf16)acc[mt][nt][r];
      }
}

// ---- scan step j (j=1..7): h0[b,c,j] = h0[b,c,j-1]@A + u[b,c,j], all (b,c) ----
// prevB = u for j==1 (h0[c,0] == u[c,0]), else hall. No barriers; M=8192.
__global__ __launch_bounds__(256) void kt_step(
    const bf16* __restrict__ u, const bf16* __restrict__ prevB,
    const bf16* __restrict__ At, bf16* __restrict__ hall, int j) {
  const int tid = threadIdx.x;
  const int wave = tid >> 6, lane = tid & 63;
  const int quad = lane >> 4, l16 = lane & 15;
  const int m0 = blockIdx.x * 32;    // m = b*256 + c
  const int b = m0 >> 8;
  const int c0 = m0 & 255;
  const int nbase = blockIdx.y * 256 + wave * 64;
  const bf16* pA0 = prevB + ((long)b * Lseq + (long)(c0 + l16) * KC + (j - 1)) * Dm;
  const bf16* pA1 = prevB + ((long)b * Lseq + (long)(c0 + 16 + l16) * KC + (j - 1)) * Dm;
  f32x4 acc[2][4] = {};
  gemm_core(pA0, pA1, At + (long)nbase * Dm, quad, l16, acc);
#pragma unroll
  for (int mt = 0; mt < 2; ++mt)
#pragma unroll
    for (int nt = 0; nt < 4; ++nt)
#pragma unroll
      for (int r = 0; r < 4; ++r) {
        int rl = mt * 16 + quad * 4 + r;
        long t = (long)(c0 + rl) * KC + j;
        int n = nbase + nt * 16 + l16;
        long off = ((long)b * Lseq + t) * Dm + n;
        float v = acc[mt][nt][r] + (float)u[off];
        hall[off] = (bf16)v;
      }
}

// ---- Kogge-Stone round: Hout[b,c] = Hin[b,c] + Hin[b,c-shift]@Q ----
// Input rows gathered via (sb,sc,off): round 0 reads summaries straight from
// hall (h0[c,7]); c-shift<0 rows read the zero row (pure copy-through).
__global__ __launch_bounds__(256) void kt_ks2(
    const bf16* __restrict__ HinB, long sb, int sc, int off,
    bf16* __restrict__ Hout, const bf16* __restrict__ Qt,
    const bf16* __restrict__ zrow, int shift) {
  const int tid = threadIdx.x;
  const int wave = tid >> 6, lane = tid & 63;
  const int quad = lane >> 4, l16 = lane & 15;
  const int m0 = blockIdx.x * 32;
  const int b = m0 >> 8;
  const int c0 = m0 & 255;
  const int nbase = blockIdx.y * 256 + wave * 64;
  const int cA0 = c0 + l16 - shift;
  const int cA1 = c0 + 16 + l16 - shift;
  const bf16* pA0 = (cA0 >= 0) ? HinB + ((long)b * sb + (long)cA0 * sc + off) * Dm : zrow;
  const bf16* pA1 = (cA1 >= 0) ? HinB + ((long)b * sb + (long)cA1 * sc + off) * Dm : zrow;
  f32x4 acc[2][4] = {};
  gemm_core(pA0, pA1, Qt + (long)nbase * Dm, quad, l16, acc);
#pragma unroll
  for (int mt = 0; mt < 2; ++mt)
#pragma unroll
    for (int nt = 0; nt < 4; ++nt)
#pragma unroll
      for (int r = 0; r < 4; ++r) {
        int c = c0 + mt * 16 + quad * 4 + r;
        int n = nbase + nt * 16 + l16;
        float v = acc[mt][nt][r] + (float)HinB[((long)b * sb + (long)c * sc + off) * Dm + n];
        Hout[((long)(b * 256 + c)) * Dm + n] = (bf16)v;
      }
}

// ---- output: y[b,c,j] = h0[b,c,j]@C + P[b,c-1]@T_{j+1}   (K=1024 fused) ----
// j = blockIdx.z; j==0 reads h0 rows from u. LDS-staged epilogue -> full-line
// dwordx4 stores (kills the 2.3x write amplification of scalar fp32 stores).
__global__ __launch_bounds__(256) void kt_out(
    const bf16* __restrict__ hall, const bf16* __restrict__ u,
    const bf16* __restrict__ P, const bf16* __restrict__ Ct,
    const bf16* __restrict__ Tt, const bf16* __restrict__ zrow,
    float* __restrict__ y) {
  __shared__ float sm[4][32][66];  // +2 pad: conflict-free b32 writes
  const int tid = threadIdx.x;
  const int wave = tid >> 6, lane = tid & 63;
  const int quad = lane >> 4, l16 = lane & 15;
  const int m0 = blockIdx.x * 32;
  const int b = m0 >> 8;
  const int c0 = m0 & 255;
  const int j = blockIdx.z;
  const int nbase = blockIdx.y * 256 + wave * 64;
  const bf16* H0B = (j == 0) ? u : hall;
  const bf16* pH0 = H0B + ((long)b * Lseq + (long)(c0 + l16) * KC + j) * Dm;
  const bf16* pH1 = H0B + ((long)b * Lseq + (long)(c0 + 16 + l16) * KC + j) * Dm;
  const int cP0 = c0 + l16 - 1;
  const bf16* pP0 = (cP0 >= 0) ? P + (long)(b * 256 + cP0) * Dm : zrow;
  const bf16* pP1 = P + (long)(b * 256 + c0 + 15 + l16) * Dm;
  f32x4 acc[2][4] = {};
  gemm_core(pH0, pH1, Ct + (long)nbase * Dm, quad, l16, acc);
  gemm_core(pP0, pP1, Tt + (long)j * Dm * Dm + (long)nbase * Dm, quad, l16, acc);
#pragma unroll
  for (int mt = 0; mt < 2; ++mt)
#pragma unroll
    for (int nt = 0; nt < 4; ++nt)
#pragma unroll
      for (int r = 0; r < 4; ++r)
        sm[wave][mt * 16 + quad * 4 + r][nt * 16 + l16] = acc[mt][nt][r];
  __syncthreads();
  const int lq = lane >> 4, ll = lane & 15;
#pragma unroll
  for (int it = 0; it < 8; ++it) {
    int rl = it * 4 + lq;
    long t = (long)(c0 + rl) * KC + j;
    float2 v0 = *reinterpret_cast<const float2*>(&sm[wave][rl][ll * 4]);
    float2 v1 = *reinterpret_cast<const float2*>(&sm[wave][rl][ll * 4 + 2]);
    f32x4 v; v[0] = v0.x; v[1] = v0.y; v[2] = v1.x; v[3] = v1.y;
    *reinterpret_cast<f32x4*>(y + ((long)b * Lseq + t) * Dm + nbase + ll * 4) = v;
  }
}

extern "C" void kernel_launch(void* const* d_in, const int* in_sizes, int n_in,
                              void* d_out, int out_size, void* d_ws, size_t ws_size,
                              hipStream_t stream) {
  const float* x  = (const float*)d_in[0];
  const float* dA = (const float*)d_in[1];
  const float* dB = (const float*)d_in[2];
  const float* Cm = (const float*)d_in[3];
  float* out = (float*)d_out;

  char* w = (char*)d_ws;
  const size_t MATB = (size_t)Dm * Dm * sizeof(bf16);  // 512 KB
  bf16* At  = (bf16*)w; w += MATB;
  bf16* Bt  = (bf16*)w; w += MATB;
  bf16* Ct  = (bf16*)w; w += MATB;
  bf16* Abf = (bf16*)w; w += MATB;
  bf16* pw[10]; bf16* pwT[10];   // pw[l] = A^(2^(l+1)); KS round i uses pwT[2+i]
  for (int l = 0; l < 10; ++l) { pw[l] = (bf16*)w; w += MATB; pwT[l] = (bf16*)w; w += MATB; }
  bf16* A3  = (bf16*)w; w += MATB;
  bf16* A3t = (bf16*)w; w += MATB;
  bf16* A5  = (bf16*)w; w += MATB;
  bf16* A6  = (bf16*)w; w += MATB;
  bf16* A7  = (bf16*)w; w += MATB;
  bf16* jkT = (bf16*)w; w += MATB;                     // junk transpose target
  bf16* Tt  = (bf16*)w; w += 8 * MATB;                 // taps (A^(j+1) C)^T
  bf16* zrow = (bf16*)w; w += 4096;                    // 512 zero bf16 (padded)
  bf16* u    = (bf16*)w; w += (size_t)32 * Lseq * Dm * sizeof(bf16);  // 64 MB
  bf16* hall = (bf16*)w; w += (size_t)32 * Lseq * Dm * sizeof(bf16);  // 64 MB h0
  bf16* P0 = (bf16*)w; w += (size_t)CH * 32 * Dm * sizeof(bf16);      // 8 MB
  bf16* P1 = (bf16*)w; w += (size_t)CH * 32 * Dm * sizeof(bf16);      // 8 MB

  // 1. pack + zero row
  kt_pack<<<dim3(Dm * Dm / 256, 3), 256, 0, stream>>>(dA, dB, Cm, At, Bt, Ct, Abf, zrow);
  // 2. u = x @ deltaB
  kt_gemm_rows<<<(32 * Lseq) / 32, 512, 0, stream>>>(x, Bt, u);
  // 3. matrix powers + taps
  kt_square<<<Dm / 32, 512, 0, stream>>>(Abf, At, pw[0], pwT[0]);          // A^2
  kt_square<<<Dm / 32, 512, 0, stream>>>(pw[0], pwT[0], pw[1], pwT[1]);    // A^4
  kt_square<<<Dm / 32, 512, 0, stream>>>(pw[1], pwT[1], pw[2], pwT[2]);    // A^8
  kt_square<<<Dm / 32, 512, 0, stream>>>(pw[0], At,     A3, A3t);          // A^3
  kt_square<<<Dm / 32, 512, 0, stream>>>(pw[1], At,     A5, jkT);          // A^5
  kt_square<<<Dm / 32, 512, 0, stream>>>(pw[1], pwT[0], A6, jkT);          // A^6
  kt_square<<<Dm / 32, 512, 0, stream>>>(pw[1], A3t,    A7, jkT);          // A^7
  kt_taps<<<dim3(Dm / 32, 8), 512, 0, stream>>>(Abf, pw[0], A3, pw[1], A5, A6, A7, pw[2], Ct, Tt);
  for (int l = 3; l < 10; ++l)                                             // A^16..A^1024
    kt_square<<<Dm / 32, 512, 0, stream>>>(pw[l - 1], pwT[l - 1], pw[l], pwT[l]);
  // 4. zero-init chunk scans, all states stored (j=0 lives in u)
  for (int j = 1; j < KC; ++j)
    kt_step<<<dim3(256, 2), 256, 0, stream>>>(u, (j == 1) ? u : hall, At, hall, j);
  // 5. Kogge-Stone over 256 chunk summaries (= hall rows j=7)
  kt_ks2<<<dim3(256, 2), 256, 0, stream>>>(hall, (long)Lseq, KC, KC - 1, P0, pwT[2], zrow, 1);
  bf16* hin = P0; bf16* hout = P1;
  for (int i = 1; i < 8; ++i) {
    kt_ks2<<<dim3(256, 2), 256, 0, stream>>>(hin, 256L, 1, 0, hout, pwT[2 + i], zrow, 1 << i);
    bf16* tmp = hin; hin = hout; hout = tmp;
  }
  // 6. fused output: y = h0@C + P_{c-1}@(A^{j+1}C)
  kt_out<<<dim3(256, 2, 8), 256, 0, stream>>>(hall, u, hin, Ct, Tt, zrow, out);
}

// Round 2
// 857.670 us; speedup vs baseline: 1.7711x; 1.7711x over previous
//
#include <hip/hip_runtime.h>

// StateSpaceModel: y = scan(h = h@A + x@B) @ C,  B=32 L=2048 D=512.
// Same verified algorithm as round 1; GEMM engine rebuilt as LDS-staged
// tiles (global_load_lds w=16, single-buffer 2-barrier loop, XOR-seg swizzle
// per rule #21: linear LDS dest + inverse-swizzled global src + swizzled read).
//   u = x@B                       (kt_gemm_rows, unchanged)
//   h0 chunk scans (stored):      7x kt_step   64x64-tile,  grid 1024
//   Kogge-Stone over 256 chunks:  8x kt_ks     64x64-tile + folded Q^2 blocks
//   y = h0@C + P_{c-1}@(A^{j+1}C) kt_out      128x128-tile, grid 2048

using bf16 = __bf16;
typedef __bf16 bf16x8 __attribute__((ext_vector_type(8)));
typedef float  f32x4  __attribute__((ext_vector_type(4)));
typedef unsigned int u32;

constexpr int Dm   = 512;
constexpr int Lseq = 2048;
constexpr int KC   = 8;    // chunk length
constexpr int CH   = 256;  // chunks

__device__ __forceinline__ bf16x8 ld8(const bf16* p) {
  return *reinterpret_cast<const bf16x8*>(p);
}
__device__ __forceinline__ bf16x8 ld8f(const float* p) {
  f32x4 lo = *reinterpret_cast<const f32x4*>(p);
  f32x4 hi = *reinterpret_cast<const f32x4*>(p + 4);
  bf16x8 r;
#pragma unroll
  for (int i = 0; i < 4; ++i) { r[i] = (bf16)lo[i]; r[i + 4] = (bf16)hi[i]; }
  return r;
}
__device__ __forceinline__ f32x4 mfma16(bf16x8 a, bf16x8 b, f32x4 c) {
  return __builtin_amdgcn_mfma_f32_16x16x32_bf16(a, b, c, 0, 0, 0);
}
// async global->LDS, 16B per lane; LDS dest = wave-uniform base + lane*16
__device__ __forceinline__ void gld16(const bf16* g, bf16* l) {
  __builtin_amdgcn_global_load_lds(
      (const __attribute__((address_space(1))) u32*)g,
      (__attribute__((address_space(3))) u32*)l, 16, 0, 0);
}

// MFMA step over one staged BKx64 tile. arow/brow = (waveRowBase+l16)*64.
// sw = l16&7: read-side XOR-seg swizzle (matches inverse-swizzled staging).
template<int WM, int WN>
__device__ __forceinline__ void mma_step(const bf16* As, const bf16* Bs,
                                         int arow, int brow, int sw, int quad,
                                         f32x4 (&acc)[WM][WN]) {
#pragma unroll
  for (int ks = 0; ks < 2; ++ks) {
    const int sg = ((ks * 4 + quad) ^ sw) * 8;
    bf16x8 a[WM], b[WN];
#pragma unroll
    for (int m = 0; m < WM; ++m) a[m] = ld8(As + arow + m * 1024 + sg);
#pragma unroll
    for (int n = 0; n < WN; ++n) b[n] = ld8(Bs + brow + n * 1024 + sg);
#pragma unroll
    for (int m = 0; m < WM; ++m)
#pragma unroll
      for (int n = 0; n < WN; ++n) acc[m][n] = mfma16(a[m], b[n], acc[m][n]);
  }
}

// ---- pack fp32->bf16: Wt[n][k] = W[k][n] for deltaA/deltaB/C, Abf=A, zero row ----
__global__ __launch_bounds__(256) void kt_pack(
    const float* __restrict__ a, const float* __restrict__ b, const float* __restrict__ c,
    bf16* __restrict__ at, bf16* __restrict__ bt, bf16* __restrict__ ct,
    bf16* __restrict__ abf, bf16* __restrict__ zrow) {
  if (blockIdx.y == 0 && blockIdx.x == 0 && threadIdx.x < 256)
    reinterpret_cast<int*>(zrow)[threadIdx.x] = 0;  // 1 KB of zeros
  int flat = blockIdx.x * 256 + threadIdx.x;
  int n = flat & (Dm - 1);
  int k = flat >> 9;
  const float* s = (blockIdx.y == 0) ? a : (blockIdx.y == 1) ? b : c;
  bf16* d        = (blockIdx.y == 0) ? at : (blockIdx.y == 1) ? bt : ct;
  float v = s[(long)k * Dm + n];
  d[(long)n * Dm + k] = (bf16)v;
  if (blockIdx.y == 0) abf[(long)k * Dm + n] = (bf16)v;
}

// ---- u = x @ deltaB : fp32 rows -> bf16 out (full-occupancy direct style) ----
__global__ __launch_bounds__(512) void kt_gemm_rows(
    const float* __restrict__ X, const bf16* __restrict__ Wt, bf16* __restrict__ O) {
  const int tid = threadIdx.x;
  const int wave = tid >> 6, lane = tid & 63;
  const int quad = lane >> 4, l16 = lane & 15;
  const long rowbase = (long)blockIdx.x * 32;
  const int nbase = wave * 64;
  f32x4 acc[2][4] = {};
  for (int kk = 0; kk < Dm; kk += 32) {
    const int kf = kk + quad * 8;
    bf16x8 a0 = ld8f(X + (rowbase + l16) * Dm + kf);
    bf16x8 a1 = ld8f(X + (rowbase + 16 + l16) * Dm + kf);
#pragma unroll
    for (int nt = 0; nt < 4; ++nt) {
      bf16x8 bw = ld8(Wt + (long)(nbase + nt * 16 + l16) * Dm + kf);
      acc[0][nt] = mfma16(a0, bw, acc[0][nt]);
      acc[1][nt] = mfma16(a1, bw, acc[1][nt]);
    }
  }
#pragma unroll
  for (int mt = 0; mt < 2; ++mt)
#pragma unroll
    for (int nt = 0; nt < 4; ++nt)
#pragma unroll
      for (int r = 0; r < 4; ++r) {
        long m = rowbase + mt * 16 + quad * 4 + r;
        int n = nbase + nt * 16 + l16;
        O[m * Dm + n] = (bf16)acc[mt][nt][r];
      }
}

// ---- S = P @ B (Pt = B^T); writes S and S^T ----
__global__ __launch_bounds__(512) void kt_square(
    const bf16* __restrict__ P, const bf16* __restrict__ Pt,
    bf16* __restrict__ S, bf16* __restrict__ St) {
  const int tid = threadIdx.x;
  const int wave = tid >> 6, lane = tid & 63;
  const int quad = lane >> 4, l16 = lane & 15;
  const long rowbase = (long)blockIdx.x * 32;
  const int nbase = wave * 64;
  f32x4 acc[2][4] = {};
  for (int kk = 0; kk < Dm; kk += 32) {
    const int kf = kk + quad * 8;
    bf16x8 a0 = ld8(P + (rowbase + l16) * Dm + kf);
    bf16x8 a1 = ld8(P + (rowbase + 16 + l16) * Dm + kf);
#pragma unroll
    for (int nt = 0; nt < 4; ++nt) {
      bf16x8 bw = ld8(Pt + (long)(nbase + nt * 16 + l16) * Dm + kf);
      acc[0][nt] = mfma16(a0, bw, acc[0][nt]);
      acc[1][nt] = mfma16(a1, bw, acc[1][nt]);
    }
  }
#pragma unroll
  for (int mt = 0; mt < 2; ++mt)
#pragma unroll
    for (int nt = 0; nt < 4; ++nt)
#pragma unroll
      for (int r = 0; r < 4; ++r) {
        long m = rowbase + mt * 16 + quad * 4 + r;
        int n = nbase + nt * 16 + l16;
        float v = acc[mt][nt][r];
        S[m * Dm + n] = (bf16)v;
        St[(long)n * Dm + m] = (bf16)v;
      }
}

// ---- taps: Tt[j] = (A^(j+1) @ C)^T, j = blockIdx.y in 0..7 ----
__global__ __launch_bounds__(512) void kt_taps(
    const bf16* __restrict__ q1, const bf16* __restrict__ q2,
    const bf16* __restrict__ q3, const bf16* __restrict__ q4,
    const bf16* __restrict__ q5, const bf16* __restrict__ q6,
    const bf16* __restrict__ q7, const bf16* __restrict__ q8,
    const bf16* __restrict__ Ct, bf16* __restrict__ Tt) {
  const int j = blockIdx.y;
  const bf16* Aop = (j == 0) ? q1 : (j == 1) ? q2 : (j == 2) ? q3 : (j == 3) ? q4
                  : (j == 4) ? q5 : (j == 5) ? q6 : (j == 6) ? q7 : q8;
  bf16* St = Tt + (long)j * Dm * Dm;
  const int tid = threadIdx.x;
  const int wave = tid >> 6, lane = tid & 63;
  const int quad = lane >> 4, l16 = lane & 15;
  const long rowbase = (long)blockIdx.x * 32;
  const int nbase = wave * 64;
  f32x4 acc[2][4] = {};
  for (int kk = 0; kk < Dm; kk += 32) {
    const int kf = kk + quad * 8;
    bf16x8 a0 = ld8(Aop + (rowbase + l16) * Dm + kf);
    bf16x8 a1 = ld8(Aop + (rowbase + 16 + l16) * Dm + kf);
#pragma unroll
    for (int nt = 0; nt < 4; ++nt) {
      bf16x8 bw = ld8(Ct + (long)(nbase + nt * 16 + l16) * Dm + kf);
      acc[0][nt] = mfma16(a0, bw, acc[0][nt]);
      acc[1][nt] = mfma16(a1, bw, acc[1][nt]);
    }
  }
#pragma unroll
  for (int mt = 0; mt < 2; ++mt)
#pragma unroll
    for (int nt = 0; nt < 4; ++nt)
#pragma unroll
      for (int r = 0; r < 4; ++r) {
        long m = rowbase + mt * 16 + quad * 4 + r;
        int n = nbase + nt * 16 + l16;
        St[(long)n * Dm + m] = (bf16)acc[mt][nt][r];
      }
}

// ---- scan step j (1..7): hall[b,c,j] = prev[b,c,j-1]@A + u[b,c,j] ----
// 64x64 tile, 4 waves of 32x32. grid (128, 8) = 1024 blocks.
__global__ __launch_bounds__(256) void kt_step(
    const bf16* __restrict__ u, const bf16* __restrict__ prevB,
    const bf16* __restrict__ At, bf16* __restrict__ hall, int j) {
  __shared__ __align__(16) bf16 As[64 * 64];
  __shared__ __align__(16) bf16 Bs[64 * 64];
  const int tid = threadIdx.x, wave = tid >> 6, lane = tid & 63;
  const int quad = lane >> 4, l16 = lane & 15;
  const int seg = tid & 7, rr0 = tid >> 3;
  const int m0 = blockIdx.x * 64, n0 = blockIdx.y * 64;
  const int b = m0 >> 8, c0 = m0 & 255;
  const bf16* aSrc[2]; const bf16* bSrc[2];
#pragma unroll
  for (int it = 0; it < 2; ++it) {
    int r = it * 32 + rr0;
    int sg = seg ^ (r & 7);   // inverse swizzle on global source
    aSrc[it] = prevB + ((long)b * Lseq + (long)(c0 + r) * KC + (j - 1)) * Dm + sg * 8;
    bSrc[it] = At + (long)(n0 + r) * Dm + sg * 8;
  }
  bf16* aL = As + wave * 512;
  bf16* bL = Bs + wave * 512;
  const int wrB = (wave >> 1) * 32, wcB = (wave & 1) * 32;
  const int arow = (wrB + l16) * 64, brow = (wcB + l16) * 64, sw = l16 & 7;
  f32x4 acc[2][2] = {};
  for (int k0 = 0; k0 < Dm; k0 += 64) {
#pragma unroll
    for (int it = 0; it < 2; ++it) {
      gld16(aSrc[it] + k0, aL + it * 2048);
      gld16(bSrc[it] + k0, bL + it * 2048);
    }
    __syncthreads();
    mma_step<2, 2>(As, Bs, arow, brow, sw, quad, acc);
    __syncthreads();
  }
#pragma unroll
  for (int m = 0; m < 2; ++m)
#pragma unroll
    for (int n = 0; n < 2; ++n)
#pragma unroll
      for (int r = 0; r < 4; ++r) {
        int row = wrB + m * 16 + quad * 4 + r;
        int col = n0 + wcB + n * 16 + l16;
        long off = ((long)b * Lseq + (long)(c0 + row) * KC + j) * Dm + col;
        hall[off] = (bf16)(acc[m][n][r] + (float)u[off]);
      }
}

// ---- KS round: Hout[b,c] = Hin[b,c] + Hin[b,c-shift]@Q; 64x64 tiles.
// grid (128, 9): y<8 main; y==8, x<64: folded squaring Snext = Q@Q (+ ^T).
__global__ __launch_bounds__(256) void kt_ks(
    const bf16* __restrict__ HinB, long sb, long sc, long off0,
    bf16* __restrict__ Hout, const bf16* __restrict__ Qt,
    const bf16* __restrict__ Q, const bf16* __restrict__ zrow,
    bf16* __restrict__ Snext, bf16* __restrict__ SnextT,
    int shift, int doSq) {
  __shared__ __align__(16) bf16 As[64 * 64];
  __shared__ __align__(16) bf16 Bs[64 * 64];
  const int tid = threadIdx.x, wave = tid >> 6, lane = tid & 63;
  const int quad = lane >> 4, l16 = lane & 15;
  const int seg = tid & 7, rr0 = tid >> 3;
  bf16* aL = As + wave * 512;
  bf16* bL = Bs + wave * 512;
  const int wrB = (wave >> 1) * 32, wcB = (wave & 1) * 32;
  const int arow = (wrB + l16) * 64, brow = (wcB + l16) * 64, sw = l16 & 7;
  f32x4 acc[2][2] = {};
  if (blockIdx.y < 8) {
    const int m0 = blockIdx.x * 64, n0 = blockIdx.y * 64;
    const int b = m0 >> 8, c0 = m0 & 255;
    const bf16* aSrc[2]; const bf16* bSrc[2];
#pragma unroll
    for (int it = 0; it < 2; ++it) {
      int r = it * 32 + rr0;
      int sg = seg ^ (r & 7);
      int c = c0 + r - shift;
      aSrc[it] = (c >= 0) ? HinB + ((long)b * sb + (long)c * sc + off0) * Dm + sg * 8
                          : zrow + sg * 8;
      bSrc[it] = Qt + (long)(n0 + r) * Dm + sg * 8;
    }
    for (int k0 = 0; k0 < Dm; k0 += 64) {
#pragma unroll
      for (int it = 0; it < 2; ++it) {
        gld16(aSrc[it] + k0, aL + it * 2048);
        gld16(bSrc[it] + k0, bL + it * 2048);
      }
      __syncthreads();
      mma_step<2, 2>(As, Bs, arow, brow, sw, quad, acc);
      __syncthreads();
    }
#pragma unroll
    for (int m = 0; m < 2; ++m)
#pragma unroll
      for (int n = 0; n < 2; ++n)
#pragma unroll
        for (int r = 0; r < 4; ++r) {
          int row = wrB + m * 16 + quad * 4 + r;
          int col = n0 + wcB + n * 16 + l16;
          int c = c0 + row;
          float v = acc[m][n][r] +
                    (float)HinB[((long)b * sb + (long)c * sc + off0) * Dm + col];
          Hout[((long)(b * 256 + c)) * Dm + col] = (bf16)v;
        }
  } else {
    if (blockIdx.x >= 64 || !doSq) return;
    const int m0 = (blockIdx.x >> 3) * 64, n0 = (blockIdx.x & 7) * 64;
    const bf16* aSrc[2]; const bf16* bSrc[2];
#pragma unroll
    for (int it = 0; it < 2; ++it) {
      int r = it * 32 + rr0;
      int sg = seg ^ (r & 7);
      aSrc[it] = Q + (long)(m0 + r) * Dm + sg * 8;
      bSrc[it] = Qt + (long)(n0 + r) * Dm + sg * 8;
    }
    for (int k0 = 0; k0 < Dm; k0 += 64) {
#pragma unroll
      for (int it = 0; it < 2; ++it) {
        gld16(aSrc[it] + k0, aL + it * 2048);
        gld16(bSrc[it] + k0, bL + it * 2048);
      }
      __syncthreads();
      mma_step<2, 2>(As, Bs, arow, brow, sw, quad, acc);
      __syncthreads();
    }
#pragma unroll
    for (int m = 0; m < 2; ++m)
#pragma unroll
      for (int n = 0; n < 2; ++n)
#pragma unroll
        for (int r = 0; r < 4; ++r) {
          int mg = m0 + wrB + m * 16 + quad * 4 + r;
          int ng = n0 + wcB + n * 16 + l16;
          float v = acc[m][n][r];
          Snext[(long)mg * Dm + ng] = (bf16)v;
          SnextT[(long)ng * Dm + mg] = (bf16)v;
        }
  }
}

// ---- output: y[b,c,j] = h0[b,c,j]@C + P[b,c-1]@T_{j+1}; 128x128 tile ----
// grid (64, 4, 8). LDS-staged fp32 epilogue -> full-line dwordx4 stores.
__global__ __launch_bounds__(256) void kt_out(
    const bf16* __restrict__ hall, const bf16* __restrict__ u,
    const bf16* __restrict__ P, const bf16* __restrict__ Ct,
    const bf16* __restrict__ Tt, const bf16* __restrict__ zrow,
    float* __restrict__ y) {
  __shared__ __align__(16) char LDSraw[32768];
  bf16* As = (bf16*)LDSraw;         // [128][64]
  bf16* Bs = As + 128 * 64;
  const int tid = threadIdx.x, wave = tid >> 6, lane = tid & 63;
  const int quad = lane >> 4, l16 = lane & 15;
  const int seg = tid & 7, rr0 = tid >> 3;
  const int m0 = blockIdx.x * 128, n0 = blockIdx.y * 128;
  const int j = blockIdx.z;
  const int b = m0 >> 8, c0 = m0 & 255;
  bf16* aL = As + wave * 512;
  bf16* bL = Bs + wave * 512;
  const int wrB = (wave >> 1) * 64, wcB = (wave & 1) * 64;
  const int arow = (wrB + l16) * 64, brow = (wcB + l16) * 64, sw = l16 & 7;
  f32x4 acc[4][4] = {};
  {  // slot A: h0[b,c,j] @ C   (j==0 rows live in u)
    const bf16* H0B = (j == 0) ? u : hall;
    const bf16* aSrc[4]; const bf16* bSrc[4];
#pragma unroll
    for (int it = 0; it < 4; ++it) {
      int r = it * 32 + rr0;
      int sg = seg ^ (r & 7);
      aSrc[it] = H0B + ((long)b * Lseq + (long)(c0 + r) * KC + j) * Dm + sg * 8;
      bSrc[it] = Ct + (long)(n0 + r) * Dm + sg * 8;
    }
    for (int k0 = 0; k0 < Dm; k0 += 64) {
#pragma unroll
      for (int it = 0; it < 4; ++it) {
        gld16(aSrc[it] + k0, aL + it * 2048);
        gld16(bSrc[it] + k0, bL + it * 2048);
      }
      __syncthreads();
      mma_step<4, 4>(As, Bs, arow, brow, sw, quad, acc);
      __syncthreads();
    }
  }
  {  // slot B: P[b,c-1] @ T_{j+1}
    const bf16* Tj = Tt + (long)j * Dm * Dm;
    const bf16* aSrc[4]; const bf16* bSrc[4];
#pragma unroll
    for (int it = 0; it < 4; ++it) {
      int r = it * 32 + rr0;
      int sg = seg ^ (r & 7);
      int c = c0 + r - 1;
      aSrc[it] = (c >= 0) ? P + (long)(b * 256 + c) * Dm + sg * 8 : zrow + sg * 8;
      bSrc[it] = Tj + (long)(n0 + r) * Dm + sg * 8;
    }
    for (int k0 = 0; k0 < Dm; k0 += 64) {
#pragma unroll
      for (int it = 0; it < 4; ++it) {
        gld16(aSrc[it] + k0, aL + it * 2048);
        gld16(bSrc[it] + k0, bL + it * 2048);
      }
      __syncthreads();
      mma_step<4, 4>(As, Bs, arow, brow, sw, quad, acc);
      __syncthreads();
    }
  }
  // epilogue: stage fp32 through LDS (reuse), write 512B-contiguous rows
  float* sm = (float*)LDSraw;  // [64][128]
  const int wr = wave >> 1;
#pragma unroll
  for (int p = 0; p < 2; ++p) {
    __syncthreads();
    if (wr == p) {
#pragma unroll
      for (int m = 0; m < 4; ++m)
#pragma unroll
        for (int n = 0; n < 4; ++n)
#pragma unroll
          for (int r = 0; r < 4; ++r)
            sm[(m * 16 + quad * 4 + r) * 128 + wcB + n * 16 + l16] = acc[m][n][r];
    }
    __syncthreads();
#pragma unroll
    for (int ch = 0; ch < 8; ++ch) {
      int chunk = ch * 256 + tid;
      int srow = chunk >> 5, cc = chunk & 31;
      f32x4 v = *reinterpret_cast<f32x4*>(&sm[srow * 128 + cc * 4]);
      long t = (long)(c0 + p * 64 + srow) * KC + j;
      *reinterpret_cast<f32x4*>(y + ((long)b * Lseq + t) * Dm + n0 + cc * 4) = v;
    }
  }
}

extern "C" void kernel_launch(void* const* d_in, const int* in_sizes, int n_in,
                              void* d_out, int out_size, void* d_ws, size_t ws_size,
                              hipStream_t stream) {
  const float* x  = (const float*)d_in[0];
  const float* dA = (const float*)d_in[1];
  const float* dB = (const float*)d_in[2];
  const float* Cm = (const float*)d_in[3];
  float* out = (float*)d_out;

  char* w = (char*)d_ws;
  const size_t MATB = (size_t)Dm * Dm * sizeof(bf16);  // 512 KB
  bf16* At  = (bf16*)w; w += MATB;
  bf16* Bt  = (bf16*)w; w += MATB;
  bf16* Ct  = (bf16*)w; w += MATB;
  bf16* Abf = (bf16*)w; w += MATB;
  bf16* pw[10]; bf16* pwT[10];   // pw[2+i] = A^(8*2^i); KS round i uses pwT[2+i]
  for (int l = 0; l < 10; ++l) { pw[l] = (bf16*)w; w += MATB; pwT[l] = (bf16*)w; w += MATB; }
  bf16* A3  = (bf16*)w; w += MATB;
  bf16* A3t = (bf16*)w; w += MATB;
  bf16* A5  = (bf16*)w; w += MATB;
  bf16* A6  = (bf16*)w; w += MATB;
  bf16* A7  = (bf16*)w; w += MATB;
  bf16* jkT = (bf16*)w; w += MATB;                     // junk transpose target
  bf16* Tt  = (bf16*)w; w += 8 * MATB;                 // taps (A^(j+1) C)^T
  bf16* zrow = (bf16*)w; w += 4096;                    // 512+ zero bf16
  bf16* u    = (bf16*)w; w += (size_t)32 * Lseq * Dm * sizeof(bf16);  // 64 MB
  bf16* hall = (bf16*)w; w += (size_t)32 * Lseq * Dm * sizeof(bf16);  // 64 MB h0
  bf16* P0 = (bf16*)w; w += (size_t)CH * 32 * Dm * sizeof(bf16);      // 8 MB
  bf16* P1 = (bf16*)w; w += (size_t)CH * 32 * Dm * sizeof(bf16);      // 8 MB

  // 1. pack + zero row
  kt_pack<<<dim3(Dm * Dm / 256, 3), 256, 0, stream>>>(dA, dB, Cm, At, Bt, Ct, Abf, zrow);
  // 2. u = x @ deltaB
  kt_gemm_rows<<<(32 * Lseq) / 32, 512, 0, stream>>>(x, Bt, u);
  // 3. matrix powers A^2..A^8 + taps (A^16..A^1024 fold into KS rounds)
  kt_square<<<Dm / 32, 512, 0, stream>>>(Abf, At, pw[0], pwT[0]);          // A^2
  kt_square<<<Dm / 32, 512, 0, stream>>>(pw[0], pwT[0], pw[1], pwT[1]);    // A^4
  kt_square<<<Dm / 32, 512, 0, stream>>>(pw[1], pwT[1], pw[2], pwT[2]);    // A^8
  kt_square<<<Dm / 32, 512, 0, stream>>>(pw[0], At,     A3, A3t);          // A^3
  kt_square<<<Dm / 32, 512, 0, stream>>>(pw[1], At,     A5, jkT);          // A^5
  kt_square<<<Dm / 32, 512, 0, stream>>>(pw[1], pwT[0], A6, jkT);          // A^6
  kt_square<<<Dm / 32, 512, 0, stream>>>(pw[1], A3t,    A7, jkT);          // A^7
  kt_taps<<<dim3(Dm / 32, 8), 512, 0, stream>>>(Abf, pw[0], A3, pw[1], A5, A6, A7, pw[2], Ct, Tt);
  // 4. zero-init chunk scans, all states stored (j=0 lives in u)
  for (int j = 1; j < KC; ++j)
    kt_step<<<dim3(128, 8), 256, 0, stream>>>(u, (j == 1) ? u : hall, At, hall, j);
  // 5. Kogge-Stone over 256 chunk summaries (= hall rows j=7), Q^2 folded in
  kt_ks<<<dim3(128, 9), 256, 0, stream>>>(hall, (long)Lseq, (long)KC, (long)(KC - 1),
                                          P0, pwT[2], pw[2], zrow, pw[3], pwT[3], 1, 1);
  bf16* hin = P0; bf16* hout = P1;
  for (int i = 1; i < 8; ++i) {
    int nx = (3 + i < 10) ? 3 + i : 9;
    kt_ks<<<dim3(128, 9), 256, 0, stream>>>(hin, 256L, 1L, 0L, hout, pwT[2 + i], pw[2 + i],
                                            zrow, pw[nx], pwT[nx], 1 << i, (i < 7) ? 1 : 0);
    bf16* tmp = hin; hin = hout; hout = tmp;
  }
  // 6. fused output: y = h0@C + P_{c-1}@(A^{j+1}C)
  kt_out<<<dim3(64, 4, 8), 256, 0, stream>>>(hall, u, hin, Ct, Tt, zrow, out);
}

// Round 3
// 733.326 us; speedup vs baseline: 2.0714x; 1.1696x over previous
//
#include <hip/hip_runtime.h>

// StateSpaceModel: y = scan(h = h@A + x@B) @ C,  B=32 L=2048 D=512.
// All phases as parallel LDS-tiled MFMA GEMMs (gld16 w=16 staging, XOR-seg
// swizzle: linear LDS dest + inverse-swizzled global src + swizzled read).
//   xb = bf16(x)                  kt_cvt      memory-bound pass
//   u = xb@B                      kt_u        128x128-tile, grid 2048
//   h0 chunk scans (stored):      7x kt_step  64x64-tile,  grid 1024
//   Kogge-Stone over 256 chunks:  8x kt_ks    64x64-tile + folded Q^2 blocks
//   y = h0@C + P_{c-1}@(A^{j+1}C) kt_out      128x128-tile, grid 2048

using bf16 = __bf16;
typedef __bf16 bf16x8 __attribute__((ext_vector_type(8)));
typedef float  f32x4  __attribute__((ext_vector_type(4)));
typedef unsigned int u32;

constexpr int Dm   = 512;
constexpr int Lseq = 2048;
constexpr int KC   = 8;    // chunk length
constexpr int CH   = 256;  // chunks

__device__ __forceinline__ bf16x8 ld8(const bf16* p) {
  return *reinterpret_cast<const bf16x8*>(p);
}
__device__ __forceinline__ bf16x8 ld8f(const float* p) {
  f32x4 lo = *reinterpret_cast<const f32x4*>(p);
  f32x4 hi = *reinterpret_cast<const f32x4*>(p + 4);
  bf16x8 r;
#pragma unroll
  for (int i = 0; i < 4; ++i) { r[i] = (bf16)lo[i]; r[i + 4] = (bf16)hi[i]; }
  return r;
}
__device__ __forceinline__ f32x4 mfma16(bf16x8 a, bf16x8 b, f32x4 c) {
  return __builtin_amdgcn_mfma_f32_16x16x32_bf16(a, b, c, 0, 0, 0);
}
// async global->LDS, 16B per lane; LDS dest = wave-uniform base + lane*16
__device__ __forceinline__ void gld16(const bf16* g, bf16* l) {
  __builtin_amdgcn_global_load_lds(
      (const __attribute__((address_space(1))) u32*)g,
      (__attribute__((address_space(3))) u32*)l, 16, 0, 0);
}

// MFMA step over one staged BKx64 tile. arow/brow = (waveRowBase+l16)*64.
// sw = l16&7: read-side XOR-seg swizzle (matches inverse-swizzled staging).
template<int WM, int WN>
__device__ __forceinline__ void mma_step(const bf16* As, const bf16* Bs,
                                         int arow, int brow, int sw, int quad,
                                         f32x4 (&acc)[WM][WN]) {
#pragma unroll
  for (int ks = 0; ks < 2; ++ks) {
    const int sg = ((ks * 4 + quad) ^ sw) * 8;
    bf16x8 a[WM], b[WN];
#pragma unroll
    for (int m = 0; m < WM; ++m) a[m] = ld8(As + arow + m * 1024 + sg);
#pragma unroll
    for (int n = 0; n < WN; ++n) b[n] = ld8(Bs + brow + n * 1024 + sg);
#pragma unroll
    for (int m = 0; m < WM; ++m)
#pragma unroll
      for (int n = 0; n < WN; ++n) acc[m][n] = mfma16(a[m], b[n], acc[m][n]);
  }
}

// ---- pack fp32->bf16: Wt[n][k] = W[k][n] for deltaA/deltaB/C, Abf=A, zero row ----
__global__ __launch_bounds__(256) void kt_pack(
    const float* __restrict__ a, const float* __restrict__ b, const float* __restrict__ c,
    bf16* __restrict__ at, bf16* __restrict__ bt, bf16* __restrict__ ct,
    bf16* __restrict__ abf, bf16* __restrict__ zrow) {
  if (blockIdx.y == 0 && blockIdx.x == 0 && threadIdx.x < 256)
    reinterpret_cast<int*>(zrow)[threadIdx.x] = 0;  // 1 KB of zeros
  int flat = blockIdx.x * 256 + threadIdx.x;
  int n = flat & (Dm - 1);
  int k = flat >> 9;
  const float* s = (blockIdx.y == 0) ? a : (blockIdx.y == 1) ? b : c;
  bf16* d        = (blockIdx.y == 0) ? at : (blockIdx.y == 1) ? bt : ct;
  float v = s[(long)k * Dm + n];
  d[(long)n * Dm + k] = (bf16)v;
  if (blockIdx.y == 0) abf[(long)k * Dm + n] = (bf16)v;
}

// ---- xb = bf16(x), pure streaming pass ----
__global__ __launch_bounds__(256) void kt_cvt(
    const float* __restrict__ x, bf16* __restrict__ xb) {
  const long total = (long)32 * Lseq * Dm;
  for (long i = ((long)blockIdx.x * 256 + threadIdx.x) * 8; i < total;
       i += (long)2048 * 256 * 8)
    *reinterpret_cast<bf16x8*>(xb + i) = ld8f(x + i);
}

// ---- u = xb @ B : 128x128 tile, grid (512, 4) ----
__global__ __launch_bounds__(256) void kt_u(
    const bf16* __restrict__ xb, const bf16* __restrict__ Bt, bf16* __restrict__ u) {
  __shared__ __align__(16) char LDSraw[36864];
  bf16* As = (bf16*)LDSraw;         // [128][64]
  bf16* Bs = As + 128 * 64;
  const int tid = threadIdx.x, wave = tid >> 6, lane = tid & 63;
  const int quad = lane >> 4, l16 = lane & 15;
  const int seg = tid & 7, rr0 = tid >> 3;
  const int m0 = blockIdx.x * 128, n0 = blockIdx.y * 128;
  bf16* aL = As + wave * 512;
  bf16* bL = Bs + wave * 512;
  const int wrB = (wave >> 1) * 64, wcB = (wave & 1) * 64;
  const int arow = (wrB + l16) * 64, brow = (wcB + l16) * 64, sw = l16 & 7;
  f32x4 acc[4][4] = {};
  const bf16* aSrc[4]; const bf16* bSrc[4];
#pragma unroll
  for (int it = 0; it < 4; ++it) {
    int r = it * 32 + rr0;
    int sg = seg ^ (r & 7);
    aSrc[it] = xb + (long)(m0 + r) * Dm + sg * 8;
    bSrc[it] = Bt + (long)(n0 + r) * Dm + sg * 8;
  }
  for (int k0 = 0; k0 < Dm; k0 += 64) {
#pragma unroll
    for (int it = 0; it < 4; ++it) {
      gld16(aSrc[it] + k0, aL + it * 2048);
      gld16(bSrc[it] + k0, bL + it * 2048);
    }
    __syncthreads();
    mma_step<4, 4>(As, Bs, arow, brow, sw, quad, acc);
    __syncthreads();
  }
  // epilogue: bf16 staged [128][136] (+8 pad), full-line bf16x8 stores
  bf16* smB = (bf16*)LDSraw;
#pragma unroll
  for (int m = 0; m < 4; ++m)
#pragma unroll
    for (int n = 0; n < 4; ++n)
#pragma unroll
      for (int r = 0; r < 4; ++r)
        smB[(wrB + m * 16 + quad * 4 + r) * 136 + wcB + n * 16 + l16] =
            (bf16)acc[m][n][r];
  __syncthreads();
#pragma unroll
  for (int it = 0; it < 8; ++it) {
    int chunk = it * 256 + tid;
    int row = chunk >> 4, c16 = chunk & 15;
    bf16x8 v = ld8(&smB[row * 136 + c16 * 8]);
    *reinterpret_cast<bf16x8*>(u + (long)(m0 + row) * Dm + n0 + c16 * 8) = v;
  }
}

// ---- S = P @ B (Pt = B^T); writes S and S^T ----
__global__ __launch_bounds__(512) void kt_square(
    const bf16* __restrict__ P, const bf16* __restrict__ Pt,
    bf16* __restrict__ S, bf16* __restrict__ St) {
  const int tid = threadIdx.x;
  const int wave = tid >> 6, lane = tid & 63;
  const int quad = lane >> 4, l16 = lane & 15;
  const long rowbase = (long)blockIdx.x * 32;
  const int nbase = wave * 64;
  f32x4 acc[2][4] = {};
  for (int kk = 0; kk < Dm; kk += 32) {
    const int kf = kk + quad * 8;
    bf16x8 a0 = ld8(P + (rowbase + l16) * Dm + kf);
    bf16x8 a1 = ld8(P + (rowbase + 16 + l16) * Dm + kf);
#pragma unroll
    for (int nt = 0; nt < 4; ++nt) {
      bf16x8 bw = ld8(Pt + (long)(nbase + nt * 16 + l16) * Dm + kf);
      acc[0][nt] = mfma16(a0, bw, acc[0][nt]);
      acc[1][nt] = mfma16(a1, bw, acc[1][nt]);
    }
  }
#pragma unroll
  for (int mt = 0; mt < 2; ++mt)
#pragma unroll
    for (int nt = 0; nt < 4; ++nt)
#pragma unroll
      for (int r = 0; r < 4; ++r) {
        long m = rowbase + mt * 16 + quad * 4 + r;
        int n = nbase + nt * 16 + l16;
        float v = acc[mt][nt][r];
        S[m * Dm + n] = (bf16)v;
        St[(long)n * Dm + m] = (bf16)v;
      }
}

// ---- taps: Tt[j] = (A^(j+1) @ C)^T, j = blockIdx.y in 0..7 ----
__global__ __launch_bounds__(512) void kt_taps(
    const bf16* __restrict__ q1, const bf16* __restrict__ q2,
    const bf16* __restrict__ q3, const bf16* __restrict__ q4,
    const bf16* __restrict__ q5, const bf16* __restrict__ q6,
    const bf16* __restrict__ q7, const bf16* __restrict__ q8,
    const bf16* __restrict__ Ct, bf16* __restrict__ Tt) {
  const int j = blockIdx.y;
  const bf16* Aop = (j == 0) ? q1 : (j == 1) ? q2 : (j == 2) ? q3 : (j == 3) ? q4
                  : (j == 4) ? q5 : (j == 5) ? q6 : (j == 6) ? q7 : q8;
  bf16* St = Tt + (long)j * Dm * Dm;
  const int tid = threadIdx.x;
  const int wave = tid >> 6, lane = tid & 63;
  const int quad = lane >> 4, l16 = lane & 15;
  const long rowbase = (long)blockIdx.x * 32;
  const int nbase = wave * 64;
  f32x4 acc[2][4] = {};
  for (int kk = 0; kk < Dm; kk += 32) {
    const int kf = kk + quad * 8;
    bf16x8 a0 = ld8(Aop + (rowbase + l16) * Dm + kf);
    bf16x8 a1 = ld8(Aop + (rowbase + 16 + l16) * Dm + kf);
#pragma unroll
    for (int nt = 0; nt < 4; ++nt) {
      bf16x8 bw = ld8(Ct + (long)(nbase + nt * 16 + l16) * Dm + kf);
      acc[0][nt] = mfma16(a0, bw, acc[0][nt]);
      acc[1][nt] = mfma16(a1, bw, acc[1][nt]);
    }
  }
#pragma unroll
  for (int mt = 0; mt < 2; ++mt)
#pragma unroll
    for (int nt = 0; nt < 4; ++nt)
#pragma unroll
      for (int r = 0; r < 4; ++r) {
        long m = rowbase + mt * 16 + quad * 4 + r;
        int n = nbase + nt * 16 + l16;
        St[(long)n * Dm + m] = (bf16)acc[mt][nt][r];
      }
}

// ---- scan step j (1..7): hall[b,c,j] = prev[b,c,j-1]@A + u[b,c,j] ----
// 64x64 tile, 4 waves of 32x32. grid (128, 8) = 1024 blocks.
__global__ __launch_bounds__(256) void kt_step(
    const bf16* __restrict__ u, const bf16* __restrict__ prevB,
    const bf16* __restrict__ At, bf16* __restrict__ hall, int j) {
  __shared__ __align__(16) bf16 As[64 * 64];
  __shared__ __align__(16) bf16 Bs[64 * 64];
  const int tid = threadIdx.x, wave = tid >> 6, lane = tid & 63;
  const int quad = lane >> 4, l16 = lane & 15;
  const int seg = tid & 7, rr0 = tid >> 3;
  const int m0 = blockIdx.x * 64, n0 = blockIdx.y * 64;
  const int b = m0 >> 8, c0 = m0 & 255;
  const bf16* aSrc[2]; const bf16* bSrc[2];
#pragma unroll
  for (int it = 0; it < 2; ++it) {
    int r = it * 32 + rr0;
    int sg = seg ^ (r & 7);   // inverse swizzle on global source
    aSrc[it] = prevB + ((long)b * Lseq + (long)(c0 + r) * KC + (j - 1)) * Dm + sg * 8;
    bSrc[it] = At + (long)(n0 + r) * Dm + sg * 8;
  }
  bf16* aL = As + wave * 512;
  bf16* bL = Bs + wave * 512;
  const int wrB = (wave >> 1) * 32, wcB = (wave & 1) * 32;
  const int arow = (wrB + l16) * 64, brow = (wcB + l16) * 64, sw = l16 & 7;
  f32x4 acc[2][2] = {};
  for (int k0 = 0; k0 < Dm; k0 += 64) {
#pragma unroll
    for (int it = 0; it < 2; ++it) {
      gld16(aSrc[it] + k0, aL + it * 2048);
      gld16(bSrc[it] + k0, bL + it * 2048);
    }
    __syncthreads();
    mma_step<2, 2>(As, Bs, arow, brow, sw, quad, acc);
    __syncthreads();
  }
#pragma unroll
  for (int m = 0; m < 2; ++m)
#pragma unroll
    for (int n = 0; n < 2; ++n)
#pragma unroll
      for (int r = 0; r < 4; ++r) {
        int row = wrB + m * 16 + quad * 4 + r;
        int col = n0 + wcB + n * 16 + l16;
        long off = ((long)b * Lseq + (long)(c0 + row) * KC + j) * Dm + col;
        hall[off] = (bf16)(acc[m][n][r] + (float)u[off]);
      }
}

// ---- KS round: Hout[b,c] = Hin[b,c] + Hin[b,c-shift]@Q; 64x64 tiles.
// grid (128, 9): y<8 main; y==8, x<64: folded squaring Snext = Q@Q (+ ^T).
__global__ __launch_bounds__(256) void kt_ks(
    const bf16* __restrict__ HinB, long sb, long sc, long off0,
    bf16* __restrict__ Hout, const bf16* __restrict__ Qt,
    const bf16* __restrict__ Q, const bf16* __restrict__ zrow,
    bf16* __restrict__ Snext, bf16* __restrict__ SnextT,
    int shift, int doSq) {
  __shared__ __align__(16) bf16 As[64 * 64];
  __shared__ __align__(16) bf16 Bs[64 * 64];
  const int tid = threadIdx.x, wave = tid >> 6, lane = tid & 63;
  const int quad = lane >> 4, l16 = lane & 15;
  const int seg = tid & 7, rr0 = tid >> 3;
  bf16* aL = As + wave * 512;
  bf16* bL = Bs + wave * 512;
  const int wrB = (wave >> 1) * 32, wcB = (wave & 1) * 32;
  const int arow = (wrB + l16) * 64, brow = (wcB + l16) * 64, sw = l16 & 7;
  f32x4 acc[2][2] = {};
  if (blockIdx.y < 8) {
    const int m0 = blockIdx.x * 64, n0 = blockIdx.y * 64;
    const int b = m0 >> 8, c0 = m0 & 255;
    const bf16* aSrc[2]; const bf16* bSrc[2];
#pragma unroll
    for (int it = 0; it < 2; ++it) {
      int r = it * 32 + rr0;
      int sg = seg ^ (r & 7);
      int c = c0 + r - shift;
      aSrc[it] = (c >= 0) ? HinB + ((long)b * sb + (long)c * sc + off0) * Dm + sg * 8
                          : zrow + sg * 8;
      bSrc[it] = Qt + (long)(n0 + r) * Dm + sg * 8;
    }
    for (int k0 = 0; k0 < Dm; k0 += 64) {
#pragma unroll
      for (int it = 0; it < 2; ++it) {
        gld16(aSrc[it] + k0, aL + it * 2048);
        gld16(bSrc[it] + k0, bL + it * 2048);
      }
      __syncthreads();
      mma_step<2, 2>(As, Bs, arow, brow, sw, quad, acc);
      __syncthreads();
    }
#pragma unroll
    for (int m = 0; m < 2; ++m)
#pragma unroll
      for (int n = 0; n < 2; ++n)
#pragma unroll
        for (int r = 0; r < 4; ++r) {
          int row = wrB + m * 16 + quad * 4 + r;
          int col = n0 + wcB + n * 16 + l16;
          int c = c0 + row;
          float v = acc[m][n][r] +
                    (float)HinB[((long)b * sb + (long)c * sc + off0) * Dm + col];
          Hout[((long)(b * 256 + c)) * Dm + col] = (bf16)v;
        }
  } else {
    if (blockIdx.x >= 64 || !doSq) return;
    const int m0 = (blockIdx.x >> 3) * 64, n0 = (blockIdx.x & 7) * 64;
    const bf16* aSrc[2]; const bf16* bSrc[2];
#pragma unroll
    for (int it = 0; it < 2; ++it) {
      int r = it * 32 + rr0;
      int sg = seg ^ (r & 7);
      aSrc[it] = Q + (long)(m0 + r) * Dm + sg * 8;
      bSrc[it] = Qt + (long)(n0 + r) * Dm + sg * 8;
    }
    for (int k0 = 0; k0 < Dm; k0 += 64) {
#pragma unroll
      for (int it = 0; it < 2; ++it) {
        gld16(aSrc[it] + k0, aL + it * 2048);
        gld16(bSrc[it] + k0, bL + it * 2048);
      }
      __syncthreads();
      mma_step<2, 2>(As, Bs, arow, brow, sw, quad, acc);
      __syncthreads();
    }
#pragma unroll
    for (int m = 0; m < 2; ++m)
#pragma unroll
      for (int n = 0; n < 2; ++n)
#pragma unroll
        for (int r = 0; r < 4; ++r) {
          int mg = m0 + wrB + m * 16 + quad * 4 + r;
          int ng = n0 + wcB + n * 16 + l16;
          float v = acc[m][n][r];
          Snext[(long)mg * Dm + ng] = (bf16)v;
          SnextT[(long)ng * Dm + mg] = (bf16)v;
        }
  }
}

// ---- output: y[b,c,j] = h0[b,c,j]@C + P[b,c-1]@T_{j+1}; 128x128 tile ----
// grid (64, 4, 8). LDS-staged fp32 epilogue -> full-line dwordx4 stores.
__global__ __launch_bounds__(256) void kt_out(
    const bf16* __restrict__ hall, const bf16* __restrict__ u,
    const bf16* __restrict__ P, const bf16* __restrict__ Ct,
    const bf16* __restrict__ Tt, const bf16* __restrict__ zrow,
    float* __restrict__ y) {
  __shared__ __align__(16) char LDSraw[32768];
  bf16* As = (bf16*)LDSraw;         // [128][64]
  bf16* Bs = As + 128 * 64;
  const int tid = threadIdx.x, wave = tid >> 6, lane = tid & 63;
  const int quad = lane >> 4, l16 = lane & 15;
  const int seg = tid & 7, rr0 = tid >> 3;
  const int m0 = blockIdx.x * 128, n0 = blockIdx.y * 128;
  const int j = blockIdx.z;
  const int b = m0 >> 8, c0 = m0 & 255;
  bf16* aL = As + wave * 512;
  bf16* bL = Bs + wave * 512;
  const int wrB = (wave >> 1) * 64, wcB = (wave & 1) * 64;
  const int arow = (wrB + l16) * 64, brow = (wcB + l16) * 64, sw = l16 & 7;
  f32x4 acc[4][4] = {};
  {  // slot A: h0[b,c,j] @ C   (j==0 rows live in u)
    const bf16* H0B = (j == 0) ? u : hall;
    const bf16* aSrc[4]; const bf16* bSrc[4];
#pragma unroll
    for (int it = 0; it < 4; ++it) {
      int r = it * 32 + rr0;
      int sg = seg ^ (r & 7);
      aSrc[it] = H0B + ((long)b * Lseq + (long)(c0 + r) * KC + j) * Dm + sg * 8;
      bSrc[it] = Ct + (long)(n0 + r) * Dm + sg * 8;
    }
    for (int k0 = 0; k0 < Dm; k0 += 64) {
#pragma unroll
      for (int it = 0; it < 4; ++it) {
        gld16(aSrc[it] + k0, aL + it * 2048);
        gld16(bSrc[it] + k0, bL + it * 2048);
      }
      __syncthreads();
      mma_step<4, 4>(As, Bs, arow, brow, sw, quad, acc);
      __syncthreads();
    }
  }
  {  // slot B: P[b,c-1] @ T_{j+1}
    const bf16* Tj = Tt + (long)j * Dm * Dm;
    const bf16* aSrc[4]; const bf16* bSrc[4];
#pragma unroll
    for (int it = 0; it < 4; ++it) {
      int r = it * 32 + rr0;
      int sg = seg ^ (r & 7);
      int c = c0 + r - 1;
      aSrc[it] = (c >= 0) ? P + (long)(b * 256 + c) * Dm + sg * 8 : zrow + sg * 8;
      bSrc[it] = Tj + (long)(n0 + r) * Dm + sg * 8;
    }
    for (int k0 = 0; k0 < Dm; k0 += 64) {
#pragma unroll
      for (int it = 0; it < 4; ++it) {
        gld16(aSrc[it] + k0, aL + it * 2048);
        gld16(bSrc[it] + k0, bL + it * 2048);
      }
      __syncthreads();
      mma_step<4, 4>(As, Bs, arow, brow, sw, quad, acc);
      __syncthreads();
    }
  }
  // epilogue: stage fp32 through LDS (reuse), write 512B-contiguous rows
  float* sm = (float*)LDSraw;  // [64][128]
  const int wr = wave >> 1;
#pragma unroll
  for (int p = 0; p < 2; ++p) {
    __syncthreads();
    if (wr == p) {
#pragma unroll
      for (int m = 0; m < 4; ++m)
#pragma unroll
        for (int n = 0; n < 4; ++n)
#pragma unroll
          for (int r = 0; r < 4; ++r)
            sm[(m * 16 + quad * 4 + r) * 128 + wcB + n * 16 + l16] = acc[m][n][r];
    }
    __syncthreads();
#pragma unroll
    for (int ch = 0; ch < 8; ++ch) {
      int chunk = ch * 256 + tid;
      int srow = chunk >> 5, cc = chunk & 31;
      f32x4 v = *reinterpret_cast<f32x4*>(&sm[srow * 128 + cc * 4]);
      long t = (long)(c0 + p * 64 + srow) * KC + j;
      *reinterpret_cast<f32x4*>(y + ((long)b * Lseq + t) * Dm + n0 + cc * 4) = v;
    }
  }
}

extern "C" void kernel_launch(void* const* d_in, const int* in_sizes, int n_in,
                              void* d_out, int out_size, void* d_ws, size_t ws_size,
                              hipStream_t stream) {
  const float* x  = (const float*)d_in[0];
  const float* dA = (const float*)d_in[1];
  const float* dB = (const float*)d_in[2];
  const float* Cm = (const float*)d_in[3];
  float* out = (float*)d_out;

  char* w = (char*)d_ws;
  const size_t MATB = (size_t)Dm * Dm * sizeof(bf16);  // 512 KB
  bf16* At  = (bf16*)w; w += MATB;
  bf16* Bt  = (bf16*)w; w += MATB;
  bf16* Ct  = (bf16*)w; w += MATB;
  bf16* Abf = (bf16*)w; w += MATB;
  bf16* pw[10]; bf16* pwT[10];   // pw[2+i] = A^(8*2^i); KS round i uses pwT[2+i]
  for (int l = 0; l < 10; ++l) { pw[l] = (bf16*)w; w += MATB; pwT[l] = (bf16*)w; w += MATB; }
  bf16* A3  = (bf16*)w; w += MATB;
  bf16* A3t = (bf16*)w; w += MATB;
  bf16* A5  = (bf16*)w; w += MATB;
  bf16* A6  = (bf16*)w; w += MATB;
  bf16* A7  = (bf16*)w; w += MATB;
  bf16* jkT = (bf16*)w; w += MATB;                     // junk transpose target
  bf16* Tt  = (bf16*)w; w += 8 * MATB;                 // taps (A^(j+1) C)^T
  bf16* zrow = (bf16*)w; w += 4096;                    // 512+ zero bf16
  bf16* u    = (bf16*)w; w += (size_t)32 * Lseq * Dm * sizeof(bf16);  // 64 MB
  bf16* hall = (bf16*)w; w += (size_t)32 * Lseq * Dm * sizeof(bf16);  // 64 MB h0
  bf16* P0 = (bf16*)w; w += (size_t)CH * 32 * Dm * sizeof(bf16);      // 8 MB
  bf16* P1 = (bf16*)w; w += (size_t)CH * 32 * Dm * sizeof(bf16);      // 8 MB
  bf16* xb = hall;   // alias: xb dead before kt_step first writes hall;
                     // hall j=0 slices are never read (kt_out j==0 uses u)

  // 1. pack + zero row; xb = bf16(x)
  kt_pack<<<dim3(Dm * Dm / 256, 3), 256, 0, stream>>>(dA, dB, Cm, At, Bt, Ct, Abf, zrow);
  kt_cvt<<<2048, 256, 0, stream>>>(x, xb);
  // 2. u = xb @ deltaB (tiled)
  kt_u<<<dim3(512, 4), 256, 0, stream>>>(xb, Bt, u);
  // 3. matrix powers A^2..A^8 + taps (A^16..A^1024 fold into KS rounds)
  kt_square<<<Dm / 32, 512, 0, stream>>>(Abf, At, pw[0], pwT[0]);          // A^2
  kt_square<<<Dm / 32, 512, 0, stream>>>(pw[0], pwT[0], pw[1], pwT[1]);    // A^4
  kt_square<<<Dm / 32, 512, 0, stream>>>(pw[1], pwT[1], pw[2], pwT[2]);    // A^8
  kt_square<<<Dm / 32, 512, 0, stream>>>(pw[0], At,     A3, A3t);          // A^3
  kt_square<<<Dm / 32, 512, 0, stream>>>(pw[1], At,     A5, jkT);          // A^5
  kt_square<<<Dm / 32, 512, 0, stream>>>(pw[1], pwT[0], A6, jkT);          // A^6
  kt_square<<<Dm / 32, 512, 0, stream>>>(pw[1], A3t,    A7, jkT);          // A^7
  kt_taps<<<dim3(Dm / 32, 8), 512, 0, stream>>>(Abf, pw[0], A3, pw[1], A5, A6, A7, pw[2], Ct, Tt);
  // 4. zero-init chunk scans, all states stored (j=0 lives in u)
  for (int j = 1; j < KC; ++j)
    kt_step<<<dim3(128, 8), 256, 0, stream>>>(u, (j == 1) ? u : hall, At, hall, j);
  // 5. Kogge-Stone over 256 chunk summaries (= hall rows j=7), Q^2 folded in
  kt_ks<<<dim3(128, 9), 256, 0, stream>>>(hall, (long)Lseq, (long)KC, (long)(KC - 1),
                                          P0, pwT[2], pw[2], zrow, pw[3], pwT[3], 1, 1);
  bf16* hin = P0; bf16* hout = P1;
  for (int i = 1; i < 8; ++i) {
    int nx = (3 + i < 10) ? 3 + i : 9;
    kt_ks<<<dim3(128, 9), 256, 0, stream>>>(hin, 256L, 1L, 0L, hout, pwT[2 + i], pw[2 + i],
                                            zrow, pw[nx], pwT[nx], 1 << i, (i < 7) ? 1 : 0);
    bf16* tmp = hin; hin = hout; hout = tmp;
  }
  // 6. fused output: y = h0@C + P_{c-1}@(A^{j+1}C)
  kt_out<<<dim3(64, 4, 8), 256, 0, stream>>>(hall, u, hin, Ct, Tt, zrow, out);
}

// Round 4
// 674.630 us; speedup vs baseline: 2.2516x; 1.0870x over previous
//
#include <hip/hip_runtime.h>

// StateSpaceModel: y = scan(h = h@A + x@B) @ C,  B=32 L=2048 D=512.
// All phases as parallel LDS-tiled MFMA GEMMs (gld16 w=16 staging, XOR-seg
// swizzle: linear LDS dest + inverse-swizzled global src + swizzled read).
//   xb = bf16(x)                  kt_cvt      memory-bound pass
//   u = xb@B                      kt_u        128x128-tile, grid 2048
//   powers A^2..A^8:              3x kt_sqz   batched-z squaring
//   h0 chunk scan (tree):         kt_tree x3  (h1 | h2,h3 | h4..h7), 128x128
//   Kogge-Stone over 256 chunks:  8x kt_ks    64x64-tile + folded Q^2 blocks
//   y = h0@C + P_{c-1}@(A^{j+1}C) kt_out      128x128-tile, grid 2048

using bf16 = __bf16;
typedef __bf16 bf16x8 __attribute__((ext_vector_type(8)));
typedef float  f32x4  __attribute__((ext_vector_type(4)));
typedef unsigned int u32;

constexpr int Dm   = 512;
constexpr int Lseq = 2048;
constexpr int KC   = 8;    // chunk length
constexpr int CH   = 256;  // chunks

__device__ __forceinline__ bf16x8 ld8(const bf16* p) {
  return *reinterpret_cast<const bf16x8*>(p);
}
__device__ __forceinline__ bf16x8 ld8f(const float* p) {
  f32x4 lo = *reinterpret_cast<const f32x4*>(p);
  f32x4 hi = *reinterpret_cast<const f32x4*>(p + 4);
  bf16x8 r;
#pragma unroll
  for (int i = 0; i < 4; ++i) { r[i] = (bf16)lo[i]; r[i + 4] = (bf16)hi[i]; }
  return r;
}
__device__ __forceinline__ f32x4 mfma16(bf16x8 a, bf16x8 b, f32x4 c) {
  return __builtin_amdgcn_mfma_f32_16x16x32_bf16(a, b, c, 0, 0, 0);
}
// async global->LDS, 16B per lane; LDS dest = wave-uniform base + lane*16
__device__ __forceinline__ void gld16(const bf16* g, bf16* l) {
  __builtin_amdgcn_global_load_lds(
      (const __attribute__((address_space(1))) u32*)g,
      (__attribute__((address_space(3))) u32*)l, 16, 0, 0);
}

// MFMA step over one staged BKx64 tile. arow/brow = (waveRowBase+l16)*64.
// sw = l16&7: read-side XOR-seg swizzle (matches inverse-swizzled staging).
template<int WM, int WN>
__device__ __forceinline__ void mma_step(const bf16* As, const bf16* Bs,
                                         int arow, int brow, int sw, int quad,
                                         f32x4 (&acc)[WM][WN]) {
#pragma unroll
  for (int ks = 0; ks < 2; ++ks) {
    const int sg = ((ks * 4 + quad) ^ sw) * 8;
    bf16x8 a[WM], b[WN];
#pragma unroll
    for (int m = 0; m < WM; ++m) a[m] = ld8(As + arow + m * 1024 + sg);
#pragma unroll
    for (int n = 0; n < WN; ++n) b[n] = ld8(Bs + brow + n * 1024 + sg);
#pragma unroll
    for (int m = 0; m < WM; ++m)
#pragma unroll
      for (int n = 0; n < WN; ++n) acc[m][n] = mfma16(a[m], b[n], acc[m][n]);
  }
}

// ---- pack fp32->bf16: Wt[n][k] = W[k][n] for deltaA/deltaB/C, Abf=A, zero row ----
__global__ __launch_bounds__(256) void kt_pack(
    const float* __restrict__ a, const float* __restrict__ b, const float* __restrict__ c,
    bf16* __restrict__ at, bf16* __restrict__ bt, bf16* __restrict__ ct,
    bf16* __restrict__ abf, bf16* __restrict__ zrow) {
  if (blockIdx.y == 0 && blockIdx.x == 0 && threadIdx.x < 256)
    reinterpret_cast<int*>(zrow)[threadIdx.x] = 0;  // 1 KB of zeros
  int flat = blockIdx.x * 256 + threadIdx.x;
  int n = flat & (Dm - 1);
  int k = flat >> 9;
  const float* s = (blockIdx.y == 0) ? a : (blockIdx.y == 1) ? b : c;
  bf16* d        = (blockIdx.y == 0) ? at : (blockIdx.y == 1) ? bt : ct;
  float v = s[(long)k * Dm + n];
  d[(long)n * Dm + k] = (bf16)v;
  if (blockIdx.y == 0) abf[(long)k * Dm + n] = (bf16)v;
}

// ---- xb = bf16(x), pure streaming pass ----
__global__ __launch_bounds__(256) void kt_cvt(
    const float* __restrict__ x, bf16* __restrict__ xb) {
  const long total = (long)32 * Lseq * Dm;
  for (long i = ((long)blockIdx.x * 256 + threadIdx.x) * 8; i < total;
       i += (long)2048 * 256 * 8)
    *reinterpret_cast<bf16x8*>(xb + i) = ld8f(x + i);
}

// ---- u = xb @ B : 128x128 tile, grid (512, 4) ----
__global__ __launch_bounds__(256) void kt_u(
    const bf16* __restrict__ xb, const bf16* __restrict__ Bt, bf16* __restrict__ u) {
  __shared__ __align__(16) char LDSraw[36864];
  bf16* As = (bf16*)LDSraw;         // [128][64]
  bf16* Bs = As + 128 * 64;
  const int tid = threadIdx.x, wave = tid >> 6, lane = tid & 63;
  const int quad = lane >> 4, l16 = lane & 15;
  const int seg = tid & 7, rr0 = tid >> 3;
  const int m0 = blockIdx.x * 128, n0 = blockIdx.y * 128;
  bf16* aL = As + wave * 512;
  bf16* bL = Bs + wave * 512;
  const int wrB = (wave >> 1) * 64, wcB = (wave & 1) * 64;
  const int arow = (wrB + l16) * 64, brow = (wcB + l16) * 64, sw = l16 & 7;
  f32x4 acc[4][4] = {};
  const bf16* aSrc[4]; const bf16* bSrc[4];
#pragma unroll
  for (int it = 0; it < 4; ++it) {
    int r = it * 32 + rr0;
    int sg = seg ^ (r & 7);
    aSrc[it] = xb + (long)(m0 + r) * Dm + sg * 8;
    bSrc[it] = Bt + (long)(n0 + r) * Dm + sg * 8;
  }
  for (int k0 = 0; k0 < Dm; k0 += 64) {
#pragma unroll
    for (int it = 0; it < 4; ++it) {
      gld16(aSrc[it] + k0, aL + it * 2048);
      gld16(bSrc[it] + k0, bL + it * 2048);
    }
    __syncthreads();
    mma_step<4, 4>(As, Bs, arow, brow, sw, quad, acc);
    __syncthreads();
  }
  // epilogue: bf16 staged [128][136] (+8 pad), full-line bf16x8 stores
  bf16* smB = (bf16*)LDSraw;
#pragma unroll
  for (int m = 0; m < 4; ++m)
#pragma unroll
    for (int n = 0; n < 4; ++n)
#pragma unroll
      for (int r = 0; r < 4; ++r)
        smB[(wrB + m * 16 + quad * 4 + r) * 136 + wcB + n * 16 + l16] =
            (bf16)acc[m][n][r];
  __syncthreads();
#pragma unroll
  for (int it = 0; it < 8; ++it) {
    int chunk = it * 256 + tid;
    int row = chunk >> 4, c16 = chunk & 15;
    bf16x8 v = ld8(&smB[row * 136 + c16 * 8]);
    *reinterpret_cast<bf16x8*>(u + (long)(m0 + row) * Dm + n0 + c16 * 8) = v;
  }
}

// ---- batched squares: job z computes S = P @ B (Pt = B^T), + S^T ----
struct SqJob { const bf16* P; const bf16* Pt; bf16* S; bf16* St; };
struct SqJobs { SqJob j[4]; };
__global__ __launch_bounds__(512) void kt_sqz(SqJobs jobs) {
  const SqJob jb = jobs.j[blockIdx.y];
  const int tid = threadIdx.x;
  const int wave = tid >> 6, lane = tid & 63;
  const int quad = lane >> 4, l16 = lane & 15;
  const long rowbase = (long)blockIdx.x * 32;
  const int nbase = wave * 64;
  f32x4 acc[2][4] = {};
  for (int kk = 0; kk < Dm; kk += 32) {
    const int kf = kk + quad * 8;
    bf16x8 a0 = ld8(jb.P + (rowbase + l16) * Dm + kf);
    bf16x8 a1 = ld8(jb.P + (rowbase + 16 + l16) * Dm + kf);
#pragma unroll
    for (int nt = 0; nt < 4; ++nt) {
      bf16x8 bw = ld8(jb.Pt + (long)(nbase + nt * 16 + l16) * Dm + kf);
      acc[0][nt] = mfma16(a0, bw, acc[0][nt]);
      acc[1][nt] = mfma16(a1, bw, acc[1][nt]);
    }
  }
#pragma unroll
  for (int mt = 0; mt < 2; ++mt)
#pragma unroll
    for (int nt = 0; nt < 4; ++nt)
#pragma unroll
      for (int r = 0; r < 4; ++r) {
        long m = rowbase + mt * 16 + quad * 4 + r;
        int n = nbase + nt * 16 + l16;
        float v = acc[mt][nt][r];
        jb.S[m * Dm + n] = (bf16)v;
        jb.St[(long)n * Dm + m] = (bf16)v;
      }
}

// ---- taps: Tt[j] = (A^(j+1) @ C)^T, j = blockIdx.y in 0..7 ----
__global__ __launch_bounds__(512) void kt_taps(
    const bf16* __restrict__ q1, const bf16* __restrict__ q2,
    const bf16* __restrict__ q3, const bf16* __restrict__ q4,
    const bf16* __restrict__ q5, const bf16* __restrict__ q6,
    const bf16* __restrict__ q7, const bf16* __restrict__ q8,
    const bf16* __restrict__ Ct, bf16* __restrict__ Tt) {
  const int j = blockIdx.y;
  const bf16* Aop = (j == 0) ? q1 : (j == 1) ? q2 : (j == 2) ? q3 : (j == 3) ? q4
                  : (j == 4) ? q5 : (j == 5) ? q6 : (j == 6) ? q7 : q8;
  bf16* St = Tt + (long)j * Dm * Dm;
  const int tid = threadIdx.x;
  const int wave = tid >> 6, lane = tid & 63;
  const int quad = lane >> 4, l16 = lane & 15;
  const long rowbase = (long)blockIdx.x * 32;
  const int nbase = wave * 64;
  f32x4 acc[2][4] = {};
  for (int kk = 0; kk < Dm; kk += 32) {
    const int kf = kk + quad * 8;
    bf16x8 a0 = ld8(Aop + (rowbase + l16) * Dm + kf);
    bf16x8 a1 = ld8(Aop + (rowbase + 16 + l16) * Dm + kf);
#pragma unroll
    for (int nt = 0; nt < 4; ++nt) {
      bf16x8 bw = ld8(Ct + (long)(nbase + nt * 16 + l16) * Dm + kf);
      acc[0][nt] = mfma16(a0, bw, acc[0][nt]);
      acc[1][nt] = mfma16(a1, bw, acc[1][nt]);
    }
  }
#pragma unroll
  for (int mt = 0; mt < 2; ++mt)
#pragma unroll
    for (int nt = 0; nt < 4; ++nt)
#pragma unroll
      for (int r = 0; r < 4; ++r) {
        long m = rowbase + mt * 16 + quad * 4 + r;
        int n = nbase + nt * 16 + l16;
        St[(long)n * Dm + m] = (bf16)acc[mt][nt][r];
      }
}

// ---- h0 tree level: out[b,c,j] for j=j0+z, from h_base (hall; u when base==0)
// h_j = h_base@A^{j-base} + sum_{s=1}^{j-base-1} u_{base+s}@A^{j-base-s} + u_j
// 128x128 tile, multi-segment K-loop; fp32 two-pass staged epilogue w/ u-add.
__global__ __launch_bounds__(256) void kt_tree(
    const bf16* __restrict__ u, const bf16* __restrict__ hall,
    const bf16* __restrict__ At, const bf16* __restrict__ A2t,
    const bf16* __restrict__ A3t, const bf16* __restrict__ A4t,
    bf16* __restrict__ out, int base, int j0) {
  __shared__ __align__(16) char LDSraw[32768];
  bf16* As = (bf16*)LDSraw;   // [128][64]
  bf16* Bs = As + 128 * 64;
  const int tid = threadIdx.x, wave = tid >> 6, lane = tid & 63;
  const int quad = lane >> 4, l16 = lane & 15;
  const int seg = tid & 7, rr0 = tid >> 3;
  const int m0 = blockIdx.x * 128, n0 = blockIdx.y * 128;
  const int j = j0 + (int)blockIdx.z;
  const int b = m0 >> 8, c0 = m0 & 255;
  bf16* aL = As + wave * 512;
  bf16* bL = Bs + wave * 512;
  const int wrB = (wave >> 1) * 64, wcB = (wave & 1) * 64;
  const int arow = (wrB + l16) * 64, brow = (wcB + l16) * 64, sw = l16 & 7;
  f32x4 acc[4][4] = {};
  const int nseg = j - base;
  for (int s = 0; s < nseg; ++s) {
    const int p = j - base - s;  // tap power
    const bf16* tp = (p == 1) ? At : (p == 2) ? A2t : (p == 3) ? A3t : A4t;
    const int tsel = (s == 0) ? base : base + s;
    const bf16* srcB = (s == 0 && base > 0) ? hall : u;
    const bf16* aSrc[4]; const bf16* bSrc[4];
#pragma unroll
    for (int it = 0; it < 4; ++it) {
      int r = it * 32 + rr0;
      int sg = seg ^ (r & 7);
      aSrc[it] = srcB + ((long)b * Lseq + (long)(c0 + r) * KC + tsel) * Dm + sg * 8;
      bSrc[it] = tp + (long)(n0 + r) * Dm + sg * 8;
    }
    for (int k0 = 0; k0 < Dm; k0 += 64) {
#pragma unroll
      for (int it = 0; it < 4; ++it) {
        gld16(aSrc[it] + k0, aL + it * 2048);
        gld16(bSrc[it] + k0, bL + it * 2048);
      }
      __syncthreads();
      mma_step<4, 4>(As, Bs, arow, brow, sw, quad, acc);
      __syncthreads();
    }
  }
  // epilogue: two-pass fp32 staging, fused +u_j, full-line bf16x8 stores
  float* sm = (float*)LDSraw;  // [64][128]
  const int wr = wave >> 1;
#pragma unroll
  for (int ppass = 0; ppass < 2; ++ppass) {
    __syncthreads();
    if (wr == ppass) {
#pragma unroll
      for (int m = 0; m < 4; ++m)
#pragma unroll
        for (int n = 0; n < 4; ++n)
#pragma unroll
          for (int r = 0; r < 4; ++r)
            sm[(m * 16 + quad * 4 + r) * 128 + wcB + n * 16 + l16] = acc[m][n][r];
    }
    __syncthreads();
#pragma unroll
    for (int it = 0; it < 4; ++it) {
      int chunk = it * 256 + tid;
      int row = chunk >> 4, cg = chunk & 15;
      f32x4 lo = *reinterpret_cast<f32x4*>(&sm[row * 128 + cg * 8]);
      f32x4 hi = *reinterpret_cast<f32x4*>(&sm[row * 128 + cg * 8 + 4]);
      long gaddr = ((long)b * Lseq + (long)(c0 + ppass * 64 + row) * KC + j) * Dm
                   + n0 + cg * 8;
      bf16x8 uv = ld8(u + gaddr);
      bf16x8 o;
#pragma unroll
      for (int i = 0; i < 4; ++i) {
        o[i]     = (bf16)(lo[i] + (float)uv[i]);
        o[i + 4] = (bf16)(hi[i] + (float)uv[i + 4]);
      }
      *reinterpret_cast<bf16x8*>(out + gaddr) = o;
    }
  }
}

// ---- KS round: Hout[b,c] = Hin[b,c] + Hin[b,c-shift]@Q; 64x64 tiles.
// grid (128, 9): y<8 main; y==8, x<64: folded squaring Snext = Q@Q (+ ^T).
__global__ __launch_bounds__(256) void kt_ks(
    const bf16* __restrict__ HinB, long sb, long sc, long off0,
    bf16* __restrict__ Hout, const bf16* __restrict__ Qt,
    const bf16* __restrict__ Q, const bf16* __restrict__ zrow,
    bf16* __restrict__ Snext, bf16* __restrict__ SnextT,
    int shift, int doSq) {
  __shared__ __align__(16) bf16 As[64 * 64];
  __shared__ __align__(16) bf16 Bs[64 * 64];
  const int tid = threadIdx.x, wave = tid >> 6, lane = tid & 63;
  const int quad = lane >> 4, l16 = lane & 15;
  const int seg = tid & 7, rr0 = tid >> 3;
  bf16* aL = As + wave * 512;
  bf16* bL = Bs + wave * 512;
  const int wrB = (wave >> 1) * 32, wcB = (wave & 1) * 32;
  const int arow = (wrB + l16) * 64, brow = (wcB + l16) * 64, sw = l16 & 7;
  f32x4 acc[2][2] = {};
  if (blockIdx.y < 8) {
    const int m0 = blockIdx.x * 64, n0 = blockIdx.y * 64;
    const int b = m0 >> 8, c0 = m0 & 255;
    const bf16* aSrc[2]; const bf16* bSrc[2];
#pragma unroll
    for (int it = 0; it < 2; ++it) {
      int r = it * 32 + rr0;
      int sg = seg ^ (r & 7);
      int c = c0 + r - shift;
      aSrc[it] = (c >= 0) ? HinB + ((long)b * sb + (long)c * sc + off0) * Dm + sg * 8
                          : zrow + sg * 8;
      bSrc[it] = Qt + (long)(n0 + r) * Dm + sg * 8;
    }
    for (int k0 = 0; k0 < Dm; k0 += 64) {
#pragma unroll
      for (int it = 0; it < 2; ++it) {
        gld16(aSrc[it] + k0, aL + it * 2048);
        gld16(bSrc[it] + k0, bL + it * 2048);
      }
      __syncthreads();
      mma_step<2, 2>(As, Bs, arow, brow, sw, quad, acc);
      __syncthreads();
    }
#pragma unroll
    for (int m = 0; m < 2; ++m)
#pragma unroll
      for (int n = 0; n < 2; ++n)
#pragma unroll
        for (int r = 0; r < 4; ++r) {
          int row = wrB + m * 16 + quad * 4 + r;
          int col = n0 + wcB + n * 16 + l16;
          int c = c0 + row;
          float v = acc[m][n][r] +
                    (float)HinB[((long)b * sb + (long)c * sc + off0) * Dm + col];
          Hout[((long)(b * 256 + c)) * Dm + col] = (bf16)v;
        }
  } else {
    if (blockIdx.x >= 64 || !doSq) return;
    const int m0 = (blockIdx.x >> 3) * 64, n0 = (blockIdx.x & 7) * 64;
    const bf16* aSrc[2]; const bf16* bSrc[2];
#pragma unroll
    for (int it = 0; it < 2; ++it) {
      int r = it * 32 + rr0;
      int sg = seg ^ (r & 7);
      aSrc[it] = Q + (long)(m0 + r) * Dm + sg * 8;
      bSrc[it] = Qt + (long)(n0 + r) * Dm + sg * 8;
    }
    for (int k0 = 0; k0 < Dm; k0 += 64) {
#pragma unroll
      for (int it = 0; it < 2; ++it) {
        gld16(aSrc[it] + k0, aL + it * 2048);
        gld16(bSrc[it] + k0, bL + it * 2048);
      }
      __syncthreads();
      mma_step<2, 2>(As, Bs, arow, brow, sw, quad, acc);
      __syncthreads();
    }
#pragma unroll
    for (int m = 0; m < 2; ++m)
#pragma unroll
      for (int n = 0; n < 2; ++n)
#pragma unroll
        for (int r = 0; r < 4; ++r) {
          int mg = m0 + wrB + m * 16 + quad * 4 + r;
          int ng = n0 + wcB + n * 16 + l16;
          float v = acc[m][n][r];
          Snext[(long)mg * Dm + ng] = (bf16)v;
          SnextT[(long)ng * Dm + mg] = (bf16)v;
        }
  }
}

// ---- output: y[b,c,j] = h0[b,c,j]@C + P[b,c-1]@T_{j+1}; 128x128 tile ----
// grid (64, 4, 8). LDS-staged fp32 epilogue -> full-line dwordx4 stores.
__global__ __launch_bounds__(256) void kt_out(
    const bf16* __restrict__ hall, const bf16* __restrict__ u,
    const bf16* __restrict__ P, const bf16* __restrict__ Ct,
    const bf16* __restrict__ Tt, const bf16* __restrict__ zrow,
    float* __restrict__ y) {
  __shared__ __align__(16) char LDSraw[32768];
  bf16* As = (bf16*)LDSraw;         // [128][64]
  bf16* Bs = As + 128 * 64;
  const int tid = threadIdx.x, wave = tid >> 6, lane = tid & 63;
  const int quad = lane >> 4, l16 = lane & 15;
  const int seg = tid & 7, rr0 = tid >> 3;
  const int m0 = blockIdx.x * 128, n0 = blockIdx.y * 128;
  const int j = blockIdx.z;
  const int b = m0 >> 8, c0 = m0 & 255;
  bf16* aL = As + wave * 512;
  bf16* bL = Bs + wave * 512;
  const int wrB = (wave >> 1) * 64, wcB = (wave & 1) * 64;
  const int arow = (wrB + l16) * 64, brow = (wcB + l16) * 64, sw = l16 & 7;
  f32x4 acc[4][4] = {};
  {  // slot A: h0[b,c,j] @ C   (j==0 rows live in u)
    const bf16* H0B = (j == 0) ? u : hall;
    const bf16* aSrc[4]; const bf16* bSrc[4];
#pragma unroll
    for (int it = 0; it < 4; ++it) {
      int r = it * 32 + rr0;
      int sg = seg ^ (r & 7);
      aSrc[it] = H0B + ((long)b * Lseq + (long)(c0 + r) * KC + j) * Dm + sg * 8;
      bSrc[it] = Ct + (long)(n0 + r) * Dm + sg * 8;
    }
    for (int k0 = 0; k0 < Dm; k0 += 64) {
#pragma unroll
      for (int it = 0; it < 4; ++it) {
        gld16(aSrc[it] + k0, aL + it * 2048);
        gld16(bSrc[it] + k0, bL + it * 2048);
      }
      __syncthreads();
      mma_step<4, 4>(As, Bs, arow, brow, sw, quad, acc);
      __syncthreads();
    }
  }
  {  // slot B: P[b,c-1] @ T_{j+1}
    const bf16* Tj = Tt + (long)j * Dm * Dm;
    const bf16* aSrc[4]; const bf16* bSrc[4];
#pragma unroll
    for (int it = 0; it < 4; ++it) {
      int r = it * 32 + rr0;
      int sg = seg ^ (r & 7);
      int c = c0 + r - 1;
      aSrc[it] = (c >= 0) ? P + (long)(b * 256 + c) * Dm + sg * 8 : zrow + sg * 8;
      bSrc[it] = Tj + (long)(n0 + r) * Dm + sg * 8;
    }
    for (int k0 = 0; k0 < Dm; k0 += 64) {
#pragma unroll
      for (int it = 0; it < 4; ++it) {
        gld16(aSrc[it] + k0, aL + it * 2048);
        gld16(bSrc[it] + k0, bL + it * 2048);
      }
      __syncthreads();
      mma_step<4, 4>(As, Bs, arow, brow, sw, quad, acc);
      __syncthreads();
    }
  }
  // epilogue: stage fp32 through LDS (reuse), write 512B-contiguous rows
  float* sm = (float*)LDSraw;  // [64][128]
  const int wr = wave >> 1;
#pragma unroll
  for (int p = 0; p < 2; ++p) {
    __syncthreads();
    if (wr == p) {
#pragma unroll
      for (int m = 0; m < 4; ++m)
#pragma unroll
        for (int n = 0; n < 4; ++n)
#pragma unroll
          for (int r = 0; r < 4; ++r)
            sm[(m * 16 + quad * 4 + r) * 128 + wcB + n * 16 + l16] = acc[m][n][r];
    }
    __syncthreads();
#pragma unroll
    for (int ch = 0; ch < 8; ++ch) {
      int chunk = ch * 256 + tid;
      int srow = chunk >> 5, cc = chunk & 31;
      f32x4 v = *reinterpret_cast<f32x4*>(&sm[srow * 128 + cc * 4]);
      long t = (long)(c0 + p * 64 + srow) * KC + j;
      *reinterpret_cast<f32x4*>(y + ((long)b * Lseq + t) * Dm + n0 + cc * 4) = v;
    }
  }
}

extern "C" void kernel_launch(void* const* d_in, const int* in_sizes, int n_in,
                              void* d_out, int out_size, void* d_ws, size_t ws_size,
                              hipStream_t stream) {
  const float* x  = (const float*)d_in[0];
  const float* dA = (const float*)d_in[1];
  const float* dB = (const float*)d_in[2];
  const float* Cm = (const float*)d_in[3];
  float* out = (float*)d_out;

  char* w = (char*)d_ws;
  const size_t MATB = (size_t)Dm * Dm * sizeof(bf16);  // 512 KB
  bf16* At  = (bf16*)w; w += MATB;
  bf16* Bt  = (bf16*)w; w += MATB;
  bf16* Ct  = (bf16*)w; w += MATB;
  bf16* Abf = (bf16*)w; w += MATB;
  bf16* pw[10]; bf16* pwT[10];   // pw[2+i] = A^(8*2^i); KS round i uses pwT[2+i]
  for (int l = 0; l < 10; ++l) { pw[l] = (bf16*)w; w += MATB; pwT[l] = (bf16*)w; w += MATB; }
  bf16* A3  = (bf16*)w; w += MATB;
  bf16* A3t = (bf16*)w; w += MATB;
  bf16* A5  = (bf16*)w; w += MATB;
  bf16* A6  = (bf16*)w; w += MATB;
  bf16* A7  = (bf16*)w; w += MATB;
  bf16* jkT = (bf16*)w; w += MATB;                     // junk transpose target
  bf16* Tt  = (bf16*)w; w += 8 * MATB;                 // taps (A^(j+1) C)^T
  bf16* zrow = (bf16*)w; w += 4096;                    // 512+ zero bf16
  bf16* u    = (bf16*)w; w += (size_t)32 * Lseq * Dm * sizeof(bf16);  // 64 MB
  bf16* hall = (bf16*)w; w += (size_t)32 * Lseq * Dm * sizeof(bf16);  // 64 MB h0
  bf16* P0 = (bf16*)w; w += (size_t)CH * 32 * Dm * sizeof(bf16);      // 8 MB
  bf16* P1 = (bf16*)w; w += (size_t)CH * 32 * Dm * sizeof(bf16);      // 8 MB
  bf16* xb = hall;   // alias: xb dead before kt_tree first writes hall;
                     // hall j=0 slices are never read (kt_out j==0 uses u)

  // 1. pack + zero row; xb = bf16(x)
  kt_pack<<<dim3(Dm * Dm / 256, 3), 256, 0, stream>>>(dA, dB, Cm, At, Bt, Ct, Abf, zrow);
  kt_cvt<<<2048, 256, 0, stream>>>(x, xb);
  // 2. u = xb @ deltaB (tiled)
  kt_u<<<dim3(512, 4), 256, 0, stream>>>(xb, Bt, u);
  // 3. matrix powers A^2..A^8 (3 batched launches) + taps
  {
    SqJobs s1 = {{{Abf, At, pw[0], pwT[0]}, {}, {}, {}}};
    kt_sqz<<<dim3(Dm / 32, 1), 512, 0, stream>>>(s1);                 // A^2
    SqJobs s2 = {{{pw[0], At, A3, A3t},          // A^3
                  {pw[0], pwT[0], pw[1], pwT[1]},// A^4
                  {}, {}}};
    kt_sqz<<<dim3(Dm / 32, 2), 512, 0, stream>>>(s2);
    SqJobs s3 = {{{pw[1], At, A5, jkT},          // A^5
                  {pw[1], pwT[0], A6, jkT},      // A^6
                  {pw[1], A3t, A7, jkT},         // A^7
                  {pw[1], pwT[1], pw[2], pwT[2]}}};  // A^8
    kt_sqz<<<dim3(Dm / 32, 4), 512, 0, stream>>>(s3);
  }
  kt_taps<<<dim3(Dm / 32, 8), 512, 0, stream>>>(Abf, pw[0], A3, pw[1], A5, A6, A7, pw[2], Ct, Tt);
  // 4. chunk-scan tree: h1 | h2,h3 | h4..h7   (h0 j=0 lives in u)
  kt_tree<<<dim3(64, 4, 1), 256, 0, stream>>>(u, hall, At, pwT[0], A3t, pwT[1], hall, 0, 1);
  kt_tree<<<dim3(64, 4, 2), 256, 0, stream>>>(u, hall, At, pwT[0], A3t, pwT[1], hall, 1, 2);
  kt_tree<<<dim3(64, 4, 4), 256, 0, stream>>>(u, hall, At, pwT[0], A3t, pwT[1], hall, 3, 4);
  // 5. Kogge-Stone over 256 chunk summaries (= hall rows j=7), Q^2 folded in
  kt_ks<<<dim3(128, 9), 256, 0, stream>>>(hall, (long)Lseq, (long)KC, (long)(KC - 1),
                                          P0, pwT[2], pw[2], zrow, pw[3], pwT[3], 1, 1);
  bf16* hin = P0; bf16* hout = P1;
  for (int i = 1; i < 8; ++i) {
    int nx = (3 + i < 10) ? 3 + i : 9;
    kt_ks<<<dim3(128, 9), 256, 0, stream>>>(hin, 256L, 1L, 0L, hout, pwT[2 + i], pw[2 + i],
                                            zrow, pw[nx], pwT[nx], 1 << i, (i < 7) ? 1 : 0);
    bf16* tmp = hin; hin = hout; hout = tmp;
  }
  // 6. fused output: y = h0@C + P_{c-1}@(A^{j+1}C)
  kt_out<<<dim3(64, 4, 8), 256, 0, stream>>>(hall, u, hin, Ct, Tt, zrow, out);
}